// Round 1
// baseline (679.469 us; speedup 1.0000x reference)
//
#include <hip/hip_runtime.h>
#include <math.h>

#define DEV __device__ __forceinline__

typedef short bf8 __attribute__((ext_vector_type(8)));   // 8 bf16 raw bits (4 VGPRs)
typedef float f32x4 __attribute__((ext_vector_type(4)));

// token row regions (ref stream order): s=0 hidden [0,4800), s=1 source [4800,9600), s=2 text [9600,10832)
#define TOK 10832

DEV unsigned short f2bf(float f) {
  union { float f; unsigned u; } x; x.f = f;
  unsigned r = x.u + 0x7fffu + ((x.u >> 16) & 1u);
  return (unsigned short)(r >> 16);
}
DEV float bf2f(unsigned short h) {
  union { unsigned u; float f; } x; x.u = ((unsigned)h) << 16; return x.f;
}

DEV void decode_row(int row, int& s, int& b, int& p) {
  if (row < 4800)      { s = 0; b = row / 300; p = row - b * 300; }
  else if (row < 9600) { s = 1; int r = row - 4800; b = r / 300; p = r - b * 300; }
  else                 { s = 2; int r = row - 9600; b = r / 77;  p = r - b * 77; }
}

DEV f32x4 MFMA(bf8 a, bf8 b, f32x4 c) {
  return __builtin_amdgcn_mfma_f32_16x16x32_bf16(a, b, c, 0, 0, 0);
}

// ---------------- weight transpose + fp32->bf16: dst[c][r] = src[r][c] --------
__global__ __launch_bounds__(256) void k_transpose(const float* __restrict__ src,
                                                   unsigned short* __restrict__ dst,
                                                   int R, int C, long sstride, long dstride) {
  __shared__ float t[32][33];
  const float* s = src + (long)blockIdx.z * sstride;
  unsigned short* d = dst + (long)blockIdx.z * dstride;
  int c0 = blockIdx.x * 32, r0 = blockIdx.y * 32;
  int tx = threadIdx.x, ty = threadIdx.y;
  #pragma unroll
  for (int i = ty; i < 32; i += 8) t[i][tx] = s[(long)(r0 + i) * C + c0 + tx];
  __syncthreads();
  #pragma unroll
  for (int i = ty; i < 32; i += 8) d[(long)(c0 + i) * R + r0 + tx] = f2bf(t[tx][i]);
}

// ---------------- ada modulation: ada[s][b][e] = silu(temb[b]) . Wada[s][:,e] + bada[s][e]
__global__ __launch_bounds__(256) void k_ada(const float* __restrict__ temb,
    const float* __restrict__ Wada, const float* __restrict__ bada, float* __restrict__ ada) {
  __shared__ float st[16][512];
  int s = blockIdx.y;
  int e = blockIdx.x * 256 + threadIdx.x;
  for (int i = threadIdx.x; i < 16 * 512; i += 256) {
    float v = temb[i];
    st[i >> 9][i & 511] = v / (1.f + __expf(-v));
  }
  __syncthreads();
  float acc[16];
  #pragma unroll
  for (int b = 0; b < 16; b++) acc[b] = 0.f;
  const float* wp = Wada + (long)s * 512 * 3072 + e;
  for (int d = 0; d < 512; d++) {
    float wv = wp[(long)d * 3072];
    #pragma unroll
    for (int b = 0; b < 16; b++) acc[b] += st[b][d] * wv;
  }
  float bv = bada[s * 3072 + e];
  #pragma unroll
  for (int b = 0; b < 16; b++) ada[((long)s * 16 + b) * 3072 + e] = acc[b] + bv;
}

// ---------------- rope tables (xpos), p in [0,300), pair f in [0,32) -----------
__global__ __launch_bounds__(256) void k_rope_tab(float* __restrict__ rc,
    float* __restrict__ rs, float* __restrict__ rsc) {
  int i = blockIdx.x * 256 + threadIdx.x;
  if (i >= 300 * 32) return;
  int p = i >> 5, f = i & 31;
  float inv = powf(10000.f, -(2.f * f) / 64.f);
  float ang = (float)p * inv;
  float base = (2.f * f + 25.6f) / 89.6f;
  float pw = (float)(p - 150) * (1.f / 512.f);
  rc[i] = cosf(ang);
  rs[i] = sinf(ang);
  rsc[i] = powf(base, pw);
}

// ---------------- LayerNorm + AdaLN modulate -> bf16 rows ---------------------
__global__ __launch_bounds__(256) void k_lnmod(const float* __restrict__ xp,
    const float* __restrict__ sp, const float* __restrict__ tp,
    const float* __restrict__ hbuf, const float* __restrict__ ada,
    unsigned short* __restrict__ outp, int chunk) {
  int row = blockIdx.x;
  int s, b, p; decode_row(row, s, b, p);
  const float* in;
  if (hbuf) in = hbuf + (long)row * 512;
  else {
    const float* basep = (s == 0) ? xp : (s == 1) ? sp : tp;
    int len = (s == 2) ? 77 : 300;
    in = basep + ((long)b * len + p) * 512;
  }
  int t = threadIdx.x;
  float v0 = in[t], v1 = in[t + 256];
  float s1 = v0 + v1, s2 = v0 * v0 + v1 * v1;
  #pragma unroll
  for (int d = 32; d; d >>= 1) { s1 += __shfl_xor(s1, d); s2 += __shfl_xor(s2, d); }
  __shared__ float r1[4], r2[4];
  int wid = t >> 6, lane = t & 63;
  if (lane == 0) { r1[wid] = s1; r2[wid] = s2; }
  __syncthreads();
  float S = r1[0] + r1[1] + r1[2] + r1[3];
  float Q = r2[0] + r2[1] + r2[2] + r2[3];
  float mean = S * (1.f / 512.f);
  float var = Q * (1.f / 512.f) - mean * mean;
  float rstd = rsqrtf(var + 1e-6f);
  const float* ap = ada + ((long)s * 16 + b) * 3072 + chunk * 512;
  float sh0 = ap[t], sh1 = ap[t + 256];
  float sc0 = ap[512 + t], sc1 = ap[512 + t + 256];
  long ob = (long)row * 512;
  outp[ob + t]       = f2bf((v0 - mean) * rstd * (1.f + sc0) + sh0);
  outp[ob + t + 256] = f2bf((v1 - mean) * rstd * (1.f + sc1) + sh1);
}

// ---------------- generic MFMA GEMM: C[M,N] = A[M,K] @ Wt[N,K]^T + bias -------
// EPI 0: write bf16 (qkv).  EPI 1: h = stream_in + g_a*(C)  -> f32.
// EPI 2: out = h + g_m*C -> d_out in concat order.
template <int EPI>
__global__ __launch_bounds__(256) void k_gemm(const unsigned short* __restrict__ A,
    const unsigned short* __restrict__ Wt, const float* __restrict__ bias,
    float* __restrict__ outF, unsigned short* __restrict__ outB,
    const float* __restrict__ hread, const float* __restrict__ ada,
    const float* __restrict__ xp, const float* __restrict__ sp, const float* __restrict__ tp,
    int K, int N) {
  int s = blockIdx.z;
  int mt = blockIdx.y;
  int Mtiles = (s == 2) ? 20 : 75;
  if (mt >= Mtiles) return;
  int Ms = (s == 2) ? 1232 : 4800;
  int rowbase = s * 4800;
  int m0 = mt * 64, n0 = blockIdx.x * 64;
  __shared__ unsigned short As[64][40];
  __shared__ unsigned short Bs[64][40];
  int tid = threadIdx.x;
  int lr = tid >> 2, lc = (tid & 3) * 8;
  int wid = tid >> 6, lane = tid & 63;
  int wr = wid >> 1, wc = wid & 1;
  int l16 = lane & 15, lg = lane >> 4;
  int arow = m0 + lr; if (arow >= Ms) arow = Ms - 1;
  const unsigned short* Ap = A + (long)(rowbase + arow) * K + lc;
  const unsigned short* Bp = Wt + ((long)s * N + n0 + lr) * K + lc;
  f32x4 acc[2][2];
  #pragma unroll
  for (int i = 0; i < 2; i++)
    #pragma unroll
    for (int j = 0; j < 2; j++) acc[i][j] = (f32x4){0.f, 0.f, 0.f, 0.f};
  for (int k0 = 0; k0 < K; k0 += 32) {
    *(uint4*)&As[lr][lc] = *(const uint4*)(Ap + k0);
    *(uint4*)&Bs[lr][lc] = *(const uint4*)(Bp + k0);
    __syncthreads();
    bf8 af[2], bfr[2];
    #pragma unroll
    for (int i = 0; i < 2; i++) {
      af[i]  = *(const bf8*)&As[wr * 32 + i * 16 + l16][lg * 8];
      bfr[i] = *(const bf8*)&Bs[wc * 32 + i * 16 + l16][lg * 8];
    }
    #pragma unroll
    for (int i = 0; i < 2; i++)
      #pragma unroll
      for (int j = 0; j < 2; j++)
        acc[i][j] = MFMA(af[i], bfr[j], acc[i][j]);
    __syncthreads();
  }
  #pragma unroll
  for (int i = 0; i < 2; i++) {
    #pragma unroll
    for (int r = 0; r < 4; r++) {
      int rloc = m0 + wr * 32 + i * 16 + lg * 4 + r;
      if (rloc >= Ms) continue;
      int grow = rowbase + rloc;
      int b, p;
      if (s == 2) { b = rloc / 77;  p = rloc - b * 77; }
      else        { b = rloc / 300; p = rloc - b * 300; }
      #pragma unroll
      for (int j = 0; j < 2; j++) {
        int col = n0 + wc * 32 + j * 16 + l16;
        float v = acc[i][j][r] + bias[s * N + col];
        if constexpr (EPI == 0) {
          outB[(long)grow * 1536 + col] = f2bf(v);
        } else if constexpr (EPI == 1) {
          const float* basep = (s == 0) ? xp : (s == 1) ? sp : tp;
          int len = (s == 2) ? 77 : 300;
          float iv = basep[((long)b * len + p) * 512 + col];
          float ga = ada[((long)s * 16 + b) * 3072 + 1024 + col];
          outF[(long)grow * 512 + col] = iv + ga * v;
        } else {
          float hv = hread[(long)grow * 512 + col];
          float gm = ada[((long)s * 16 + b) * 3072 + 2560 + col];
          int l = ((s == 0) ? 377 : (s == 1) ? 77 : 0) + p;
          outF[((long)b * 677 + l) * 512 + col] = hv + gm * v;
        }
      }
    }
  }
}

// ---------------- FF1 GEMM with fused GEGLU (lin & gate tiles together) -------
__global__ __launch_bounds__(256) void k_gemm_geglu(const unsigned short* __restrict__ A,
    const unsigned short* __restrict__ Wt, const float* __restrict__ bias,
    unsigned short* __restrict__ gout) {
  int s = blockIdx.z;
  int mt = blockIdx.y;
  int Mtiles = (s == 2) ? 20 : 75;
  if (mt >= Mtiles) return;
  int Ms = (s == 2) ? 1232 : 4800;
  int rowbase = s * 4800;
  int m0 = mt * 64, n0 = blockIdx.x * 64;
  const unsigned short* Ws = Wt + (long)s * 4096 * 512;
  __shared__ unsigned short As[64][40];
  __shared__ unsigned short Bl[64][40];
  __shared__ unsigned short Bg[64][40];
  int tid = threadIdx.x;
  int lr = tid >> 2, lc = (tid & 3) * 8;
  int wid = tid >> 6, lane = tid & 63;
  int wr = wid >> 1, wc = wid & 1;
  int l16 = lane & 15, lg = lane >> 4;
  int arow = m0 + lr; if (arow >= Ms) arow = Ms - 1;
  const unsigned short* Ap  = A + (long)(rowbase + arow) * 512 + lc;
  const unsigned short* Blp = Ws + (long)(n0 + lr) * 512 + lc;
  const unsigned short* Bgp = Ws + (long)(2048 + n0 + lr) * 512 + lc;
  f32x4 accl[2][2], accg[2][2];
  #pragma unroll
  for (int i = 0; i < 2; i++)
    #pragma unroll
    for (int j = 0; j < 2; j++) {
      accl[i][j] = (f32x4){0.f, 0.f, 0.f, 0.f};
      accg[i][j] = (f32x4){0.f, 0.f, 0.f, 0.f};
    }
  for (int k0 = 0; k0 < 512; k0 += 32) {
    *(uint4*)&As[lr][lc] = *(const uint4*)(Ap + k0);
    *(uint4*)&Bl[lr][lc] = *(const uint4*)(Blp + k0);
    *(uint4*)&Bg[lr][lc] = *(const uint4*)(Bgp + k0);
    __syncthreads();
    bf8 af[2], bl[2], bg[2];
    #pragma unroll
    for (int i = 0; i < 2; i++) {
      af[i] = *(const bf8*)&As[wr * 32 + i * 16 + l16][lg * 8];
      bl[i] = *(const bf8*)&Bl[wc * 32 + i * 16 + l16][lg * 8];
      bg[i] = *(const bf8*)&Bg[wc * 32 + i * 16 + l16][lg * 8];
    }
    #pragma unroll
    for (int i = 0; i < 2; i++)
      #pragma unroll
      for (int j = 0; j < 2; j++) {
        accl[i][j] = MFMA(af[i], bl[j], accl[i][j]);
        accg[i][j] = MFMA(af[i], bg[j], accg[i][j]);
      }
    __syncthreads();
  }
  #pragma unroll
  for (int i = 0; i < 2; i++) {
    #pragma unroll
    for (int r = 0; r < 4; r++) {
      int rloc = m0 + wr * 32 + i * 16 + lg * 4 + r;
      if (rloc >= Ms) continue;
      int grow = rowbase + rloc;
      #pragma unroll
      for (int j = 0; j < 2; j++) {
        int col = n0 + wc * 32 + j * 16 + l16;
        float lv = accl[i][j][r] + bias[s * 4096 + col];
        float gv = accg[i][j][r] + bias[s * 4096 + 2048 + col];
        float g  = lv * 0.5f * gv * (1.f + erff(gv * 0.70710678118654752f));
        gout[(long)grow * 2048 + col] = f2bf(g);
      }
    }
  }
}

// ---------------- RMS-norm + rope/pos-embed + attention layout ----------------
__global__ __launch_bounds__(256) void k_rmsrope(const unsigned short* __restrict__ qkv,
    const float* __restrict__ gqk, const float* __restrict__ posq, const float* __restrict__ posk,
    const float* __restrict__ rcos, const float* __restrict__ rsin, const float* __restrict__ rscl,
    unsigned short* __restrict__ qb, unsigned short* __restrict__ kb,
    unsigned short* __restrict__ vtb) {
  int gw = (blockIdx.x * 256 + threadIdx.x) >> 6;
  int lane = threadIdx.x & 63;
  int token = gw >> 3, h = gw & 7;
  if (token >= TOK) return;
  int s, b, p; decode_row(token, s, b, p);
  long base = (long)token * 1536 + h * 64 + lane;
  float q = bf2f(qkv[base]);
  float k = bf2f(qkv[base + 512]);
  float v = bf2f(qkv[base + 1024]);
  float sq = q * q, sk = k * k;
  #pragma unroll
  for (int d = 32; d; d >>= 1) { sq += __shfl_xor(sq, d); sk += __shfl_xor(sk, d); }
  q *= rsqrtf(sq * (1.f / 64.f) + 1e-6f) * gqk[s * 128 + lane];
  k *= rsqrtf(sk * (1.f / 64.f) + 1e-6f) * gqk[s * 128 + 64 + lane];
  int l;
  if (s == 2) {
    l = p;
    q += posq[p * 64 + lane];
    k += posk[p * 64 + lane];
  } else {
    l = (s == 1 ? 77 : 377) + p;
    int pr = lane >> 1;
    float c = rcos[p * 32 + pr], sn = rsin[p * 32 + pr], sc = rscl[p * 32 + pr];
    float qo = __shfl_xor(q, 1), ko = __shfl_xor(k, 1);
    float sgn = (lane & 1) ? 1.f : -1.f;
    q = (q * c + sgn * qo * sn) * sc;
    k = (k * c + sgn * ko * sn) / sc;
  }
  long bh = (long)(b * 8 + h);
  long qi = (bh * 677 + l) * 64 + lane;
  qb[qi] = f2bf(q);
  kb[qi] = f2bf(k);
  vtb[(bh * 64 + lane) * 704 + l] = f2bf(v);
}

// ---------------- flash attention: 16-row Q tile per wave, 32-key chunks ------
__global__ __launch_bounds__(256) void k_attn(const unsigned short* __restrict__ qb,
    const unsigned short* __restrict__ kb, const unsigned short* __restrict__ vtb,
    const int* __restrict__ valid, unsigned short* __restrict__ ob) {
  int bh = blockIdx.y, b = bh >> 3, h = bh & 7;
  __shared__ float biasv[704];
  __shared__ unsigned short Plds[4][16][32];
  int tid = threadIdx.x;
  for (int i = tid; i < 704; i += 256)
    biasv[i] = (i < 677 && valid[b * 677 + i] != 0) ? 0.f : -1e30f;
  __syncthreads();
  int wid = tid >> 6, lane = tid & 63;
  int qt = (blockIdx.x * 4 + wid) * 16;
  if (qt >= 677) return;
  const unsigned short* qbase = qb + (long)bh * 677 * 64;
  const unsigned short* kbase = kb + (long)bh * 677 * 64;
  const unsigned short* vbase = vtb + (long)bh * 64 * 704;
  int l16 = lane & 15, lg = lane >> 4;
  int qr = qt + l16; if (qr > 676) qr = 676;
  bf8 qf0 = *(const bf8*)(qbase + (long)qr * 64 + lg * 8);
  bf8 qf1 = *(const bf8*)(qbase + (long)qr * 64 + 32 + lg * 8);
  float m[4], lsum[4];
  f32x4 Oc[4];
  bool vqok[4];
  int qrow[4];
  #pragma unroll
  for (int c = 0; c < 4; c++) Oc[c] = (f32x4){0.f, 0.f, 0.f, 0.f};
  #pragma unroll
  for (int r = 0; r < 4; r++) {
    m[r] = -1e30f; lsum[r] = 0.f;
    qrow[r] = qt + lg * 4 + r;
    vqok[r] = (qrow[r] < 677) && (biasv[qrow[r]] == 0.f);
  }
  for (int kt = 0; kt < 677; kt += 32) {
    f32x4 S0 = (f32x4){0.f,0.f,0.f,0.f}, S1 = (f32x4){0.f,0.f,0.f,0.f};
    {
      int kr = kt + l16; int krc = kr > 676 ? 676 : kr;
      const unsigned short* kp = kbase + (long)krc * 64 + lg * 8;
      S0 = MFMA(qf0, *(const bf8*)kp, S0);
      S0 = MFMA(qf1, *(const bf8*)(kp + 32), S0);
      kr = kt + 16 + l16; krc = kr > 676 ? 676 : kr;
      kp = kbase + (long)krc * 64 + lg * 8;
      S1 = MFMA(qf0, *(const bf8*)kp, S1);
      S1 = MFMA(qf1, *(const bf8*)(kp + 32), S1);
    }
    int c0k = kt + l16, c1k = kt + 16 + l16;
    float bv0 = biasv[c0k];
    float bv1 = biasv[c1k];
    float mt[4];
    #pragma unroll
    for (int r = 0; r < 4; r++) {
      float s0 = S0[r] * 0.125f, s1 = S1[r] * 0.125f;
      bool ok0 = (c0k < 677) && ((vqok[r] && bv0 == 0.f) || (c0k == qrow[r]));
      bool ok1 = (c1k < 677) && ((vqok[r] && bv1 == 0.f) || (c1k == qrow[r]));
      s0 = ok0 ? s0 : -1e30f;
      s1 = ok1 ? s1 : -1e30f;
      S0[r] = s0; S1[r] = s1;
      mt[r] = fmaxf(s0, s1);
    }
    #pragma unroll
    for (int d = 1; d < 16; d <<= 1) {
      #pragma unroll
      for (int r = 0; r < 4; r++) mt[r] = fmaxf(mt[r], __shfl_xor(mt[r], d));
    }
    #pragma unroll
    for (int r = 0; r < 4; r++) {
      float mn = fmaxf(m[r], mt[r]);
      float corr = __expf(m[r] - mn);
      m[r] = mn;
      float p0 = __expf(S0[r] - mn);
      float p1 = __expf(S1[r] - mn);
      S0[r] = p0; S1[r] = p1;
      float ls = p0 + p1;
      #pragma unroll
      for (int d = 1; d < 16; d <<= 1) ls += __shfl_xor(ls, d);
      lsum[r] = lsum[r] * corr + ls;
      #pragma unroll
      for (int c = 0; c < 4; c++) Oc[c][r] *= corr;
    }
    #pragma unroll
    for (int r = 0; r < 4; r++) {
      Plds[wid][lg * 4 + r][l16]      = f2bf(S0[r]);
      Plds[wid][lg * 4 + r][16 + l16] = f2bf(S1[r]);
    }
    bf8 pf = *(const bf8*)&Plds[wid][l16][lg * 8];
    #pragma unroll
    for (int c = 0; c < 4; c++) {
      const unsigned short* vp = vbase + (long)(c * 16 + l16) * 704 + kt + lg * 8;
      Oc[c] = MFMA(pf, *(const bf8*)vp, Oc[c]);
    }
  }
  #pragma unroll
  for (int r = 0; r < 4; r++) {
    int l = qrow[r];
    if (l >= 677) continue;
    float inv = 1.f / fmaxf(lsum[r], 1e-30f);
    int orow;
    if (l < 77)       orow = 9600 + b * 77 + l;
    else if (l < 377) orow = 4800 + b * 300 + (l - 77);
    else              orow = b * 300 + (l - 377);
    long obase = (long)orow * 512 + h * 64;
    #pragma unroll
    for (int c = 0; c < 4; c++)
      ob[obase + c * 16 + l16] = f2bf(Oc[c][r] * inv);
  }
}

// -----------------------------------------------------------------------------
extern "C" void kernel_launch(void* const* d_in, const int* in_sizes, int n_in,
                              void* d_out, int out_size, void* d_ws, size_t ws_size,
                              hipStream_t stream) {
  const float* xp   = (const float*)d_in[0];
  const float* sp   = (const float*)d_in[1];
  const float* tp   = (const float*)d_in[2];
  const float* temb = (const float*)d_in[3];
  const float* Wqkv = (const float*)d_in[4];
  const float* bqkv = (const float*)d_in[5];
  const float* Wo   = (const float*)d_in[6];
  const float* bo   = (const float*)d_in[7];
  const float* gqk  = (const float*)d_in[8];
  const float* Wada = (const float*)d_in[9];
  const float* bada = (const float*)d_in[10];
  const float* Wff1 = (const float*)d_in[11];
  const float* bff1 = (const float*)d_in[12];
  const float* Wff2 = (const float*)d_in[13];
  const float* bff2 = (const float*)d_in[14];
  const float* posq = (const float*)d_in[15];
  const float* posk = (const float*)d_in[16];
  const int*   valid= (const int*)d_in[17];
  float* out = (float*)d_out;

  char* w = (char*)d_ws;
  size_t off = 0;
  auto take = [&](size_t bytes) -> char* {
    char* p = w + off;
    off = (off + bytes + 255) & ~(size_t)255;
    return p;
  };
  unsigned short* wqkvT = (unsigned short*)take(3UL * 1536 * 512 * 2);
  unsigned short* woT   = (unsigned short*)take(3UL * 512 * 512 * 2);
  unsigned short* wff1T = (unsigned short*)take(3UL * 4096 * 512 * 2);
  unsigned short* wff2T = (unsigned short*)take(3UL * 512 * 2048 * 2);
  float*          adab  = (float*)take(3UL * 16 * 3072 * 4);
  float*          rcosb = (float*)take(300UL * 32 * 4);
  float*          rsinb = (float*)take(300UL * 32 * 4);
  float*          rsclb = (float*)take(300UL * 32 * 4);
  unsigned short* nbuf  = (unsigned short*)take((size_t)TOK * 512 * 2);
  unsigned short* qkvb  = (unsigned short*)take((size_t)TOK * 1536 * 2);
  unsigned short* qbf   = (unsigned short*)take(16UL * 8 * 677 * 64 * 2);
  unsigned short* kbf   = (unsigned short*)take(16UL * 8 * 677 * 64 * 2);
  unsigned short* vtb   = (unsigned short*)take(16UL * 8 * 64 * 704 * 2);
  unsigned short* obuf  = (unsigned short*)take((size_t)TOK * 512 * 2);
  float*          hb    = (float*)take((size_t)TOK * 512 * 4);
  unsigned short* n2b   = (unsigned short*)take((size_t)TOK * 512 * 2);
  unsigned short* gbuf  = (unsigned short*)take((size_t)TOK * 2048 * 2);
  (void)ws_size; (void)in_sizes; (void)n_in; (void)out_size;

  // weight conversion / transposition
  k_transpose<<<dim3(16, 16, 9), dim3(32, 8), 0, stream>>>(Wqkv, wqkvT, 512, 512, 262144L, 262144L);
  k_transpose<<<dim3(16, 16, 3), dim3(32, 8), 0, stream>>>(Wo, woT, 512, 512, 262144L, 262144L);
  k_transpose<<<dim3(128, 16, 3), dim3(32, 8), 0, stream>>>(Wff1, wff1T, 512, 4096, 2097152L, 2097152L);
  k_transpose<<<dim3(16, 64, 3), dim3(32, 8), 0, stream>>>(Wff2, wff2T, 2048, 512, 1048576L, 1048576L);
  // modulation + rope tables
  k_ada<<<dim3(12, 3), 256, 0, stream>>>(temb, Wada, bada, adab);
  k_rope_tab<<<38, 256, 0, stream>>>(rcosb, rsinb, rsclb);
  // pre-attn LN+mod
  k_lnmod<<<TOK, 256, 0, stream>>>(xp, sp, tp, nullptr, adab, nbuf, 0);
  // QKV projection
  k_gemm<0><<<dim3(24, 75, 3), 256, 0, stream>>>(nbuf, wqkvT, bqkv, nullptr, qkvb, nullptr,
                                                 adab, xp, sp, tp, 512, 1536);
  // RMS + rope + layout
  k_rmsrope<<<21664, 256, 0, stream>>>(qkvb, gqk, posq, posk, rcosb, rsinb, rsclb, qbf, kbf, vtb);
  // attention
  k_attn<<<dim3(11, 128), 256, 0, stream>>>(qbf, kbf, vtb, valid, obuf);
  // out-proj + residual gate -> h
  k_gemm<1><<<dim3(8, 75, 3), 256, 0, stream>>>(obuf, woT, bo, hb, nullptr, nullptr,
                                                adab, xp, sp, tp, 512, 512);
  // post LN+mod
  k_lnmod<<<TOK, 256, 0, stream>>>(xp, sp, tp, hb, adab, n2b, 3);
  // FF1 + GEGLU
  k_gemm_geglu<<<dim3(32, 75, 3), 256, 0, stream>>>(n2b, wff1T, bff1, gbuf);
  // FF2 + final residual -> d_out
  k_gemm<2><<<dim3(8, 75, 3), 256, 0, stream>>>(gbuf, wff2T, bff2, out, nullptr, hb,
                                                adab, xp, sp, tp, 2048, 512);
}

// Round 3
// 672.240 us; speedup vs baseline: 1.0108x; 1.0108x over previous
//
#include <hip/hip_runtime.h>
#include <math.h>

#define DEV __device__ __forceinline__

typedef short bf8 __attribute__((ext_vector_type(8)));   // 8 bf16 raw bits (4 VGPRs)
typedef float f32x4 __attribute__((ext_vector_type(4)));

#define TOK 10832

DEV unsigned short f2bf(float f) {
  union { float f; unsigned u; } x; x.f = f;
  unsigned r = x.u + 0x7fffu + ((x.u >> 16) & 1u);
  return (unsigned short)(r >> 16);
}
DEV float bf2f(unsigned short h) {
  union { unsigned u; float f; } x; x.u = ((unsigned)h) << 16; return x.f;
}
DEV unsigned cvtpk(float lo, float hi) {
  unsigned r;
  asm("v_cvt_pk_bf16_f32 %0, %1, %2" : "=v"(r) : "v"(lo), "v"(hi));
  return r;
}
DEV void decode_row(int row, int& s, int& b, int& p) {
  if (row < 4800)      { s = 0; b = row / 300; p = row - b * 300; }
  else if (row < 9600) { s = 1; int r = row - 4800; b = r / 300; p = r - b * 300; }
  else                 { s = 2; int r = row - 9600; b = r / 77;  p = r - b * 77; }
}
DEV f32x4 MFMA(bf8 a, bf8 b, f32x4 c) {
  return __builtin_amdgcn_mfma_f32_16x16x32_bf16(a, b, c, 0, 0, 0);
}
DEV void gld16(const unsigned short* g, unsigned short* l) {
  __builtin_amdgcn_global_load_lds((const __attribute__((address_space(1))) unsigned int*)g,
                                   (__attribute__((address_space(3))) unsigned int*)l,
                                   16, 0, 0);
}
DEV void vmdrain() { asm volatile("s_waitcnt vmcnt(0)" ::: "memory"); }

// ---------------- weight transpose + fp32->bf16: dst[c][r] = src[r][c] --------
__global__ __launch_bounds__(256) void k_transpose(const float* __restrict__ src,
                                                   unsigned short* __restrict__ dst,
                                                   int R, int C, long sstride, long dstride) {
  __shared__ float t[32][33];
  const float* s = src + (long)blockIdx.z * sstride;
  unsigned short* d = dst + (long)blockIdx.z * dstride;
  int c0 = blockIdx.x * 32, r0 = blockIdx.y * 32;
  int tx = threadIdx.x, ty = threadIdx.y;
  #pragma unroll
  for (int i = ty; i < 32; i += 8) t[i][tx] = s[(long)(r0 + i) * C + c0 + tx];
  __syncthreads();
  #pragma unroll
  for (int i = ty; i < 32; i += 8) d[(long)(c0 + i) * R + r0 + tx] = f2bf(t[tx][i]);
}

// ---------------- ada modulation ----------------------------------------------
__global__ __launch_bounds__(256) void k_ada(const float* __restrict__ temb,
    const float* __restrict__ Wada, const float* __restrict__ bada, float* __restrict__ ada) {
  __shared__ float st[16][512];
  int s = blockIdx.y;
  int e = blockIdx.x * 256 + threadIdx.x;
  for (int i = threadIdx.x; i < 16 * 512; i += 256) {
    float v = temb[i];
    st[i >> 9][i & 511] = v / (1.f + __expf(-v));
  }
  __syncthreads();
  float acc[16];
  #pragma unroll
  for (int b = 0; b < 16; b++) acc[b] = 0.f;
  const float* wp = Wada + (long)s * 512 * 3072 + e;
  for (int d = 0; d < 512; d++) {
    float wv = wp[(long)d * 3072];
    #pragma unroll
    for (int b = 0; b < 16; b++) acc[b] += st[b][d] * wv;
  }
  float bv = bada[s * 3072 + e];
  #pragma unroll
  for (int b = 0; b < 16; b++) ada[((long)s * 16 + b) * 3072 + e] = acc[b] + bv;
}

// ---------------- rope tables (xpos) ------------------------------------------
__global__ __launch_bounds__(256) void k_rope_tab(float* __restrict__ rc,
    float* __restrict__ rs, float* __restrict__ rsc) {
  int i = blockIdx.x * 256 + threadIdx.x;
  if (i >= 300 * 32) return;
  int p = i >> 5, f = i & 31;
  float inv = powf(10000.f, -(2.f * f) / 64.f);
  float ang = (float)p * inv;
  float base = (2.f * f + 25.6f) / 89.6f;
  float pw = (float)(p - 150) * (1.f / 512.f);
  rc[i] = cosf(ang);
  rs[i] = sinf(ang);
  rsc[i] = powf(base, pw);
}

// ---------------- zero attention padding (rows/cols 677..703) -----------------
// Removes ALL read-before-write of workspace: padding regions of qb/kb/vtb are
// read by k_attn (masked arithmetically, but must be deterministic state).
__global__ __launch_bounds__(256) void k_padzero(unsigned short* __restrict__ qb,
    unsigned short* __restrict__ kb, unsigned short* __restrict__ vtb) {
  int bh = blockIdx.x, t = threadIdx.x;
  for (int i = t; i < 27 * 64; i += 256) {
    int r = 677 + (i >> 6), c = i & 63;
    long idx = ((long)bh * 704 + r) * 64 + c;
    qb[idx] = 0; kb[idx] = 0;
  }
  for (int i = t; i < 64 * 27; i += 256) {
    int r = i / 27, c = 677 + (i - r * 27);
    vtb[((long)bh * 64 + r) * 704 + c] = 0;
  }
}

// ---------------- LayerNorm + AdaLN modulate -> bf16 rows ---------------------
__global__ __launch_bounds__(256) void k_lnmod(const float* __restrict__ xp,
    const float* __restrict__ sp, const float* __restrict__ tp,
    const float* __restrict__ hbuf, const float* __restrict__ ada,
    unsigned short* __restrict__ outp, int chunk) {
  int row = blockIdx.x;
  int s, b, p; decode_row(row, s, b, p);
  const float* in;
  if (hbuf) in = hbuf + (long)row * 512;
  else {
    const float* basep = (s == 0) ? xp : (s == 1) ? sp : tp;
    int len = (s == 2) ? 77 : 300;
    in = basep + ((long)b * len + p) * 512;
  }
  int t = threadIdx.x;
  float v0 = in[t], v1 = in[t + 256];
  float s1 = v0 + v1, s2 = v0 * v0 + v1 * v1;
  #pragma unroll
  for (int d = 32; d; d >>= 1) { s1 += __shfl_xor(s1, d); s2 += __shfl_xor(s2, d); }
  __shared__ float r1[4], r2[4];
  int wid = t >> 6, lane = t & 63;
  if (lane == 0) { r1[wid] = s1; r2[wid] = s2; }
  __syncthreads();
  float S = r1[0] + r1[1] + r1[2] + r1[3];
  float Q = r2[0] + r2[1] + r2[2] + r2[3];
  float mean = S * (1.f / 512.f);
  float var = Q * (1.f / 512.f) - mean * mean;
  float rstd = rsqrtf(var + 1e-6f);
  const float* ap = ada + ((long)s * 16 + b) * 3072 + chunk * 512;
  float sh0 = ap[t], sh1 = ap[t + 256];
  float sc0 = ap[512 + t], sc1 = ap[512 + t + 256];
  long ob = (long)row * 512;
  outp[ob + t]       = f2bf((v0 - mean) * rstd * (1.f + sc0) + sh0);
  outp[ob + t + 256] = f2bf((v1 - mean) * rstd * (1.f + sc1) + sh1);
}

// ---------------- 128x128 MFMA GEMM (m97 structure) ---------------------------
template <int EPI>
__global__ __launch_bounds__(256) void k_gemm128(const unsigned short* __restrict__ A,
    const unsigned short* __restrict__ Wt, const float* __restrict__ bias,
    float* __restrict__ outF, unsigned short* __restrict__ outB,
    const float* __restrict__ hread, const float* __restrict__ ada,
    const float* __restrict__ xp, const float* __restrict__ sp, const float* __restrict__ tp,
    int K, int N) {
  int s = blockIdx.z;
  int mt = blockIdx.y;
  int Mtiles = (s == 2) ? 10 : 38;
  if (mt >= Mtiles) return;
  int Ms = (s == 2) ? 1232 : 4800;
  int rowbase = s * 4800;
  int m0 = mt * 128, n0 = blockIdx.x * 128;
  __shared__ unsigned short As[2][4096];
  __shared__ unsigned short Bs[2][4096];
  int tid = threadIdx.x;
  int w = tid >> 6, lane = tid & 63;
  int wr = w >> 1, wc = w & 1;
  int l16 = lane & 15, lg = lane >> 4;
  const unsigned short* Ag = A + (long)rowbase * K;
  const unsigned short* Bg = Wt + (long)s * N * K;
  int lrow = lane >> 2, lcol = (lane & 3) * 8;
  int ar[2], br[2];
  #pragma unroll
  for (int rnd = 0; rnd < 2; rnd++) {
    int rr = (w * 2 + rnd) * 16 + lrow;
    int a_ = m0 + rr; if (a_ >= Ms) a_ = Ms - 1;
    ar[rnd] = a_;
    br[rnd] = n0 + rr;
  }
  f32x4 acc[4][4];
  #pragma unroll
  for (int i = 0; i < 4; i++)
    #pragma unroll
    for (int j = 0; j < 4; j++) acc[i][j] = (f32x4){0.f, 0.f, 0.f, 0.f};
  #pragma unroll
  for (int rnd = 0; rnd < 2; rnd++) {
    gld16(Ag + (long)ar[rnd] * K + lcol, &As[0][(w * 2 + rnd) * 512]);
    gld16(Bg + (long)br[rnd] * K + lcol, &Bs[0][(w * 2 + rnd) * 512]);
  }
  vmdrain();
  __syncthreads();
  int buf = 0;
  for (int k0 = 0; k0 < K; k0 += 32) {
    int nx = k0 + 32;
    if (nx < K) {
      #pragma unroll
      for (int rnd = 0; rnd < 2; rnd++) {
        gld16(Ag + (long)ar[rnd] * K + nx + lcol, &As[buf ^ 1][(w * 2 + rnd) * 512]);
        gld16(Bg + (long)br[rnd] * K + nx + lcol, &Bs[buf ^ 1][(w * 2 + rnd) * 512]);
      }
    }
    bf8 af[4], bv[4];
    #pragma unroll
    for (int i = 0; i < 4; i++) {
      af[i] = *(const bf8*)&As[buf][(wr * 64 + i * 16 + l16) * 32 + lg * 8];
      bv[i] = *(const bf8*)&Bs[buf][(wc * 64 + i * 16 + l16) * 32 + lg * 8];
    }
    #pragma unroll
    for (int i = 0; i < 4; i++)
      #pragma unroll
      for (int j = 0; j < 4; j++)
        acc[i][j] = MFMA(af[i], bv[j], acc[i][j]);
    vmdrain();
    __syncthreads();
    buf ^= 1;
  }
  #pragma unroll
  for (int i = 0; i < 4; i++) {
    #pragma unroll
    for (int r = 0; r < 4; r++) {
      int rloc = m0 + wr * 64 + i * 16 + lg * 4 + r;
      if (rloc >= Ms) continue;
      int grow = rowbase + rloc;
      int b, p;
      if (s == 2) { b = rloc / 77;  p = rloc - b * 77; }
      else        { b = rloc / 300; p = rloc - b * 300; }
      #pragma unroll
      for (int j = 0; j < 4; j++) {
        int col = n0 + wc * 64 + j * 16 + l16;
        float v = acc[i][j][r] + bias[s * N + col];
        if constexpr (EPI == 0) {
          outB[(long)grow * 1536 + col] = f2bf(v);
        } else if constexpr (EPI == 1) {
          const float* basep = (s == 0) ? xp : (s == 1) ? sp : tp;
          int len = (s == 2) ? 77 : 300;
          float iv = basep[((long)b * len + p) * 512 + col];
          float ga = ada[((long)s * 16 + b) * 3072 + 1024 + col];
          outF[(long)grow * 512 + col] = iv + ga * v;
        } else {
          float hv = hread[(long)grow * 512 + col];
          float gm = ada[((long)s * 16 + b) * 3072 + 2560 + col];
          int l = ((s == 0) ? 377 : (s == 1) ? 77 : 0) + p;
          outF[((long)b * 677 + l) * 512 + col] = hv + gm * v;
        }
      }
    }
  }
}

// ---------------- FF1 GEMM (128x64 lin + 128x64 gate) + fused GEGLU -----------
__global__ __launch_bounds__(256) void k_geglu128(const unsigned short* __restrict__ A,
    const unsigned short* __restrict__ Wt, const float* __restrict__ bias,
    unsigned short* __restrict__ gout) {
  int s = blockIdx.z;
  int mt = blockIdx.y;
  int Mtiles = (s == 2) ? 10 : 38;
  if (mt >= Mtiles) return;
  int Ms = (s == 2) ? 1232 : 4800;
  int rowbase = s * 4800;
  int m0 = mt * 128, n0 = blockIdx.x * 64;
  __shared__ unsigned short As[2][4096];
  __shared__ unsigned short Bl[2][2048];
  __shared__ unsigned short Bg[2][2048];
  int tid = threadIdx.x;
  int w = tid >> 6, lane = tid & 63;
  int l16 = lane & 15, lg = lane >> 4;
  const unsigned short* Ag = A + (long)rowbase * 512;
  const unsigned short* Ws = Wt + (long)s * 4096 * 512;
  int lrow = lane >> 2, lcol = (lane & 3) * 8;
  int ar[2];
  #pragma unroll
  for (int rnd = 0; rnd < 2; rnd++) {
    int a_ = m0 + (w * 2 + rnd) * 16 + lrow; if (a_ >= Ms) a_ = Ms - 1;
    ar[rnd] = a_;
  }
  int blr = n0 + w * 16 + lrow;          // lin row
  int bgr = 2048 + n0 + w * 16 + lrow;   // gate row
  f32x4 accl[2][4], accg[2][4];
  #pragma unroll
  for (int i = 0; i < 2; i++)
    #pragma unroll
    for (int j = 0; j < 4; j++) {
      accl[i][j] = (f32x4){0.f, 0.f, 0.f, 0.f};
      accg[i][j] = (f32x4){0.f, 0.f, 0.f, 0.f};
    }
  #pragma unroll
  for (int rnd = 0; rnd < 2; rnd++)
    gld16(Ag + (long)ar[rnd] * 512 + lcol, &As[0][(w * 2 + rnd) * 512]);
  gld16(Ws + (long)blr * 512 + lcol, &Bl[0][w * 512]);
  gld16(Ws + (long)bgr * 512 + lcol, &Bg[0][w * 512]);
  vmdrain();
  __syncthreads();
  int buf = 0;
  for (int k0 = 0; k0 < 512; k0 += 32) {
    int nx = k0 + 32;
    if (nx < 512) {
      #pragma unroll
      for (int rnd = 0; rnd < 2; rnd++)
        gld16(Ag + (long)ar[rnd] * 512 + nx + lcol, &As[buf ^ 1][(w * 2 + rnd) * 512]);
      gld16(Ws + (long)blr * 512 + nx + lcol, &Bl[buf ^ 1][w * 512]);
      gld16(Ws + (long)bgr * 512 + nx + lcol, &Bg[buf ^ 1][w * 512]);
    }
    bf8 af[2], bl[4], bg[4];
    #pragma unroll
    for (int i = 0; i < 2; i++)
      af[i] = *(const bf8*)&As[buf][(w * 32 + i * 16 + l16) * 32 + lg * 8];
    #pragma unroll
    for (int j = 0; j < 4; j++) {
      bl[j] = *(const bf8*)&Bl[buf][(j * 16 + l16) * 32 + lg * 8];
      bg[j] = *(const bf8*)&Bg[buf][(j * 16 + l16) * 32 + lg * 8];
    }
    #pragma unroll
    for (int i = 0; i < 2; i++)
      #pragma unroll
      for (int j = 0; j < 4; j++) {
        accl[i][j] = MFMA(af[i], bl[j], accl[i][j]);
        accg[i][j] = MFMA(af[i], bg[j], accg[i][j]);
      }
    vmdrain();
    __syncthreads();
    buf ^= 1;
  }
  #pragma unroll
  for (int i = 0; i < 2; i++) {
    #pragma unroll
    for (int r = 0; r < 4; r++) {
      int rloc = m0 + w * 32 + i * 16 + lg * 4 + r;
      if (rloc >= Ms) continue;
      int grow = rowbase + rloc;
      #pragma unroll
      for (int j = 0; j < 4; j++) {
        int col = n0 + j * 16 + l16;
        float lv = accl[i][j][r] + bias[s * 4096 + col];
        float gv = accg[i][j][r] + bias[s * 4096 + 2048 + col];
        float g  = lv * 0.5f * gv * (1.f + erff(gv * 0.70710678118654752f));
        gout[(long)grow * 2048 + col] = f2bf(g);
      }
    }
  }
}

// ---------------- RMS-norm + rope/pos-embed + attention layout ----------------
__global__ __launch_bounds__(256) void k_rmsrope(const unsigned short* __restrict__ qkv,
    const float* __restrict__ gqk, const float* __restrict__ posq, const float* __restrict__ posk,
    const float* __restrict__ rcos, const float* __restrict__ rsin, const float* __restrict__ rscl,
    unsigned short* __restrict__ qb, unsigned short* __restrict__ kb,
    unsigned short* __restrict__ vtb) {
  int gw = (blockIdx.x * 256 + threadIdx.x) >> 6;
  int lane = threadIdx.x & 63;
  int token = gw >> 3, h = gw & 7;
  if (token >= TOK) return;
  int s, b, p; decode_row(token, s, b, p);
  long base = (long)token * 1536 + h * 64 + lane;
  float q = bf2f(qkv[base]);
  float k = bf2f(qkv[base + 512]);
  float v = bf2f(qkv[base + 1024]);
  float sq = q * q, sk = k * k;
  #pragma unroll
  for (int d = 32; d; d >>= 1) { sq += __shfl_xor(sq, d); sk += __shfl_xor(sk, d); }
  q *= rsqrtf(sq * (1.f / 64.f) + 1e-6f) * gqk[s * 128 + lane];
  k *= rsqrtf(sk * (1.f / 64.f) + 1e-6f) * gqk[s * 128 + 64 + lane];
  int l;
  if (s == 2) {
    l = p;
    q += posq[p * 64 + lane];
    k += posk[p * 64 + lane];
  } else {
    l = (s == 1 ? 77 : 377) + p;
    int pr = lane >> 1;
    float c = rcos[p * 32 + pr], sn = rsin[p * 32 + pr], sc = rscl[p * 32 + pr];
    float qo = __shfl_xor(q, 1), ko = __shfl_xor(k, 1);
    float sgn = (lane & 1) ? 1.f : -1.f;
    q = (q * c + sgn * qo * sn) * sc;
    k = (k * c + sgn * ko * sn) / sc;
  }
  long bh = (long)(b * 8 + h);
  long qi = (bh * 704 + l) * 64 + lane;
  qb[qi] = f2bf(q);
  kb[qi] = f2bf(k);
  vtb[(bh * 64 + lane) * 704 + l] = f2bf(v);
}

// ---------------- flash attention, swapped-operand, static-max softmax --------
__global__ __launch_bounds__(256) void k_attn(const unsigned short* __restrict__ qb,
    const unsigned short* __restrict__ kb, const unsigned short* __restrict__ vtb,
    const int* __restrict__ valid, unsigned short* __restrict__ ob) {
  int f0 = blockIdx.x;
  int fp = (f0 & 7) * 176 + (f0 >> 3);   // XCD-chunked bijective swizzle (1408 = 8*176)
  int bh = fp / 11, qtile = fp - bh * 11;
  int b = bh >> 3, h = bh & 7;
  __shared__ float biasv[704];
  int tid = threadIdx.x;
  for (int i = tid; i < 704; i += 256)
    biasv[i] = (i < 677 && valid[b * 677 + i] != 0) ? 0.f : -1e30f;
  __syncthreads();
  int wid = tid >> 6, lane = tid & 63;
  int qt = (qtile * 4 + wid) * 16;
  if (qt >= 677) return;
  const unsigned short* qbase = qb + (long)bh * 704 * 64;
  const unsigned short* kbase = kb + (long)bh * 704 * 64;
  const unsigned short* vbase = vtb + (long)bh * 64 * 704;
  int l16 = lane & 15, lg = lane >> 4;
  int qrow = qt + l16;
  bf8 qf0 = *(const bf8*)(qbase + (long)qrow * 64 + lg * 8);
  bf8 qf1 = *(const bf8*)(qbase + (long)qrow * 64 + 32 + lg * 8);
  float bq = biasv[qrow];
  float lsum = 0.f;
  f32x4 Oc[4];
  #pragma unroll
  for (int df = 0; df < 4; df++) Oc[df] = (f32x4){0.f, 0.f, 0.f, 0.f};
  union U { bf8 v; unsigned u[4]; uint2 d[2]; };
  for (int kt = 0; kt < 704; kt += 64) {
    f32x4 S[4];
    #pragma unroll
    for (int f = 0; f < 4; f++) {
      const unsigned short* kp = kbase + (long)(kt + f * 16 + l16) * 64 + lg * 8;
      f32x4 sa = (f32x4){0.f, 0.f, 0.f, 0.f};
      sa = MFMA(*(const bf8*)kp, qf0, sa);
      sa = MFMA(*(const bf8*)(kp + 32), qf1, sa);
      S[f] = sa;
    }
    float psum = 0.f;
    unsigned pk[4][2];
    #pragma unroll
    for (int f = 0; f < 4; f++) {
      f32x4 bk = *(const f32x4*)&biasv[kt + f * 16 + lg * 4];
      float pr[4];
      #pragma unroll
      for (int r = 0; r < 4; r++) {
        int key = kt + f * 16 + lg * 4 + r;
        bool ok = (bq + bk[r] == 0.f) || (key == qrow);
        float sv = ok ? fmaf(S[f][r], 0.125f, -20.f) : -1e30f;
        float pv = __expf(sv);
        pr[r] = pv;
        psum += pv;
      }
      pk[f][0] = cvtpk(pr[0], pr[1]);
      pk[f][1] = cvtpk(pr[2], pr[3]);
    }
    psum += __shfl_xor(psum, 16);
    psum += __shfl_xor(psum, 32);
    lsum += psum;
    #pragma unroll
    for (int c = 0; c < 2; c++) {
      U pu;
      pu.u[0] = pk[2 * c][0]; pu.u[1] = pk[2 * c][1];
      pu.u[2] = pk[2 * c + 1][0]; pu.u[3] = pk[2 * c + 1][1];
      #pragma unroll
      for (int df = 0; df < 4; df++) {
        const unsigned short* vp = vbase + (long)(df * 16 + l16) * 704 + kt + c * 32 + lg * 4;
        U vu;
        vu.d[0] = *(const uint2*)vp;
        vu.d[1] = *(const uint2*)(vp + 16);
        Oc[df] = MFMA(vu.v, pu.v, Oc[df]);
      }
    }
  }
  if (qrow < 677) {
    float inv = 1.f / lsum;
    int l = qrow;
    int orow = (l < 77) ? 9600 + b * 77 + l
             : (l < 377) ? 4800 + b * 300 + (l - 77)
                         : b * 300 + (l - 377);
    unsigned short* op = ob + (long)orow * 512 + h * 64;
    #pragma unroll
    for (int df = 0; df < 4; df++) {
      uint2 st;
      st.x = cvtpk(Oc[df][0] * inv, Oc[df][1] * inv);
      st.y = cvtpk(Oc[df][2] * inv, Oc[df][3] * inv);
      *(uint2*)(op + df * 16 + lg * 4) = st;
    }
  }
}

// -----------------------------------------------------------------------------
extern "C" void kernel_launch(void* const* d_in, const int* in_sizes, int n_in,
                              void* d_out, int out_size, void* d_ws, size_t ws_size,
                              hipStream_t stream) {
  const float* xp   = (const float*)d_in[0];
  const float* sp   = (const float*)d_in[1];
  const float* tp   = (const float*)d_in[2];
  const float* temb = (const float*)d_in[3];
  const float* Wqkv = (const float*)d_in[4];
  const float* bqkv = (const float*)d_in[5];
  const float* Wo   = (const float*)d_in[6];
  const float* bo   = (const float*)d_in[7];
  const float* gqk  = (const float*)d_in[8];
  const float* Wada = (const float*)d_in[9];
  const float* bada = (const float*)d_in[10];
  const float* Wff1 = (const float*)d_in[11];
  const float* bff1 = (const float*)d_in[12];
  const float* Wff2 = (const float*)d_in[13];
  const float* bff2 = (const float*)d_in[14];
  const float* posq = (const float*)d_in[15];
  const float* posk = (const float*)d_in[16];
  const int*   valid= (const int*)d_in[17];
  float* out = (float*)d_out;

  char* w = (char*)d_ws;
  size_t off = 0;
  auto take = [&](size_t bytes) -> char* {
    char* p = w + off;
    off = (off + bytes + 255) & ~(size_t)255;
    return p;
  };
  unsigned short* wqkvT = (unsigned short*)take(3UL * 1536 * 512 * 2);
  unsigned short* woT   = (unsigned short*)take(3UL * 512 * 512 * 2);
  unsigned short* wff1T = (unsigned short*)take(3UL * 4096 * 512 * 2);
  unsigned short* wff2T = (unsigned short*)take(3UL * 512 * 2048 * 2);
  float*          adab  = (float*)take(3UL * 16 * 3072 * 4);
  float*          rcosb = (float*)take(300UL * 32 * 4);
  float*          rsinb = (float*)take(300UL * 32 * 4);
  float*          rsclb = (float*)take(300UL * 32 * 4);
  unsigned short* nbuf  = (unsigned short*)take((size_t)TOK * 512 * 2);
  unsigned short* qkvb  = (unsigned short*)take((size_t)TOK * 1536 * 2);
  unsigned short* qbf   = (unsigned short*)take(16UL * 8 * 704 * 64 * 2);
  unsigned short* kbf   = (unsigned short*)take(16UL * 8 * 704 * 64 * 2);
  unsigned short* vtb   = (unsigned short*)take(16UL * 8 * 64 * 704 * 2);
  unsigned short* obuf  = (unsigned short*)take((size_t)TOK * 512 * 2);
  float*          hb    = (float*)take((size_t)TOK * 512 * 4);
  unsigned short* n2b   = (unsigned short*)take((size_t)TOK * 512 * 2);
  unsigned short* gbuf  = (unsigned short*)take((size_t)TOK * 2048 * 2);
  (void)ws_size; (void)in_sizes; (void)n_in; (void)out_size;

  k_transpose<<<dim3(16, 16, 9), dim3(32, 8), 0, stream>>>(Wqkv, wqkvT, 512, 512, 262144L, 262144L);
  k_transpose<<<dim3(16, 16, 3), dim3(32, 8), 0, stream>>>(Wo, woT, 512, 512, 262144L, 262144L);
  k_transpose<<<dim3(128, 16, 3), dim3(32, 8), 0, stream>>>(Wff1, wff1T, 512, 4096, 2097152L, 2097152L);
  k_transpose<<<dim3(16, 64, 3), dim3(32, 8), 0, stream>>>(Wff2, wff2T, 2048, 512, 1048576L, 1048576L);
  k_ada<<<dim3(12, 3), 256, 0, stream>>>(temb, Wada, bada, adab);
  k_rope_tab<<<38, 256, 0, stream>>>(rcosb, rsinb, rsclb);
  k_padzero<<<128, 256, 0, stream>>>(qbf, kbf, vtb);
  k_lnmod<<<TOK, 256, 0, stream>>>(xp, sp, tp, nullptr, adab, nbuf, 0);
  // QKV projection (128x128 tiles)
  k_gemm128<0><<<dim3(12, 38, 3), 256, 0, stream>>>(nbuf, wqkvT, bqkv, nullptr, qkvb, nullptr,
                                                    adab, xp, sp, tp, 512, 1536);
  k_rmsrope<<<21664, 256, 0, stream>>>(qkvb, gqk, posq, posk, rcosb, rsinb, rsclb, qbf, kbf, vtb);
  k_attn<<<1408, 256, 0, stream>>>(qbf, kbf, vtb, valid, obuf);
  // out-proj + residual gate -> h
  k_gemm128<1><<<dim3(4, 38, 3), 256, 0, stream>>>(obuf, woT, bo, hb, nullptr, nullptr,
                                                   adab, xp, sp, tp, 512, 512);
  k_lnmod<<<TOK, 256, 0, stream>>>(xp, sp, tp, hb, adab, n2b, 3);
  // FF1 + GEGLU
  k_geglu128<<<dim3(32, 38, 3), 256, 0, stream>>>(n2b, wff1T, bff1, gbuf);
  // FF2 + final residual -> d_out
  k_gemm128<2><<<dim3(4, 38, 3), 256, 0, stream>>>(gbuf, wff2T, bff2, out, nullptr, hb,
                                                   adab, xp, sp, tp, 2048, 512);
}

// Round 4
// 550.409 us; speedup vs baseline: 1.2345x; 1.2213x over previous
//
#include <hip/hip_runtime.h>
#include <math.h>

#define DEV __device__ __forceinline__

typedef short bf8 __attribute__((ext_vector_type(8)));   // 8 bf16 raw bits (4 VGPRs)
typedef float f32x4 __attribute__((ext_vector_type(4)));

#define TOK 10832

DEV unsigned short f2bf(float f) {
  union { float f; unsigned u; } x; x.f = f;
  unsigned r = x.u + 0x7fffu + ((x.u >> 16) & 1u);
  return (unsigned short)(r >> 16);
}
DEV float bf2f(unsigned short h) {
  union { unsigned u; float f; } x; x.u = ((unsigned)h) << 16; return x.f;
}
DEV unsigned cvtpk(float lo, float hi) {
  unsigned r;
  asm("v_cvt_pk_bf16_f32 %0, %1, %2" : "=v"(r) : "v"(lo), "v"(hi));
  return r;
}
DEV void decode_row(int row, int& s, int& b, int& p) {
  if (row < 4800)      { s = 0; b = row / 300; p = row - b * 300; }
  else if (row < 9600) { s = 1; int r = row - 4800; b = r / 300; p = r - b * 300; }
  else                 { s = 2; int r = row - 9600; b = r / 77;  p = r - b * 77; }
}
DEV f32x4 MFMA(bf8 a, bf8 b, f32x4 c) {
  return __builtin_amdgcn_mfma_f32_16x16x32_bf16(a, b, c, 0, 0, 0);
}
DEV void gld16(const unsigned short* g, unsigned short* l) {
  __builtin_amdgcn_global_load_lds((const __attribute__((address_space(1))) unsigned int*)g,
                                   (__attribute__((address_space(3))) unsigned int*)l,
                                   16, 0, 0);
}
DEV void vmdrain() { asm volatile("s_waitcnt vmcnt(0)" ::: "memory"); }

// ---------------- weight transpose + fp32->bf16: dst[c][r] = src[r][c] --------
__global__ __launch_bounds__(256) void k_transpose(const float* __restrict__ src,
                                                   unsigned short* __restrict__ dst,
                                                   int R, int C, long sstride, long dstride) {
  __shared__ float t[32][33];
  const float* s = src + (long)blockIdx.z * sstride;
  unsigned short* d = dst + (long)blockIdx.z * dstride;
  int c0 = blockIdx.x * 32, r0 = blockIdx.y * 32;
  int tx = threadIdx.x, ty = threadIdx.y;
  #pragma unroll
  for (int i = ty; i < 32; i += 8) t[i][tx] = s[(long)(r0 + i) * C + c0 + tx];
  __syncthreads();
  #pragma unroll
  for (int i = ty; i < 32; i += 8) d[(long)(c0 + i) * R + r0 + tx] = f2bf(t[tx][i]);
}

// ---------------- ada modulation ----------------------------------------------
__global__ __launch_bounds__(256) void k_ada(const float* __restrict__ temb,
    const float* __restrict__ Wada, const float* __restrict__ bada, float* __restrict__ ada) {
  __shared__ float st[16][512];
  int s = blockIdx.y;
  int e = blockIdx.x * 256 + threadIdx.x;
  for (int i = threadIdx.x; i < 16 * 512; i += 256) {
    float v = temb[i];
    st[i >> 9][i & 511] = v / (1.f + __expf(-v));
  }
  __syncthreads();
  float acc[16];
  #pragma unroll
  for (int b = 0; b < 16; b++) acc[b] = 0.f;
  const float* wp = Wada + (long)s * 512 * 3072 + e;
  for (int d = 0; d < 512; d++) {
    float wv = wp[(long)d * 3072];
    #pragma unroll
    for (int b = 0; b < 16; b++) acc[b] += st[b][d] * wv;
  }
  float bv = bada[s * 3072 + e];
  #pragma unroll
  for (int b = 0; b < 16; b++) ada[((long)s * 16 + b) * 3072 + e] = acc[b] + bv;
}

// ---------------- rope tables (xpos) ------------------------------------------
__global__ __launch_bounds__(256) void k_rope_tab(float* __restrict__ rc,
    float* __restrict__ rs, float* __restrict__ rsc) {
  int i = blockIdx.x * 256 + threadIdx.x;
  if (i >= 300 * 32) return;
  int p = i >> 5, f = i & 31;
  float inv = powf(10000.f, -(2.f * f) / 64.f);
  float ang = (float)p * inv;
  float base = (2.f * f + 25.6f) / 89.6f;
  float pw = (float)(p - 150) * (1.f / 512.f);
  rc[i] = cosf(ang);
  rs[i] = sinf(ang);
  rsc[i] = powf(base, pw);
}

// ---------------- zero attention padding (rows/cols 677..703) -----------------
__global__ __launch_bounds__(256) void k_padzero(unsigned short* __restrict__ qb,
    unsigned short* __restrict__ kb, unsigned short* __restrict__ vtb) {
  int bh = blockIdx.x, t = threadIdx.x;
  for (int i = t; i < 27 * 64; i += 256) {
    int r = 677 + (i >> 6), c = i & 63;
    long idx = ((long)bh * 704 + r) * 64 + c;
    qb[idx] = 0; kb[idx] = 0;
  }
  for (int i = t; i < 64 * 27; i += 256) {
    int r = i / 27, c = 677 + (i - r * 27);
    vtb[((long)bh * 64 + r) * 704 + c] = 0;
  }
}

// ---------------- LayerNorm + AdaLN modulate -> bf16 rows ---------------------
__global__ __launch_bounds__(256) void k_lnmod(const float* __restrict__ xp,
    const float* __restrict__ sp, const float* __restrict__ tp,
    const float* __restrict__ hbuf, const float* __restrict__ ada,
    unsigned short* __restrict__ outp, int chunk) {
  int row = blockIdx.x;
  int s, b, p; decode_row(row, s, b, p);
  const float* in;
  if (hbuf) in = hbuf + (long)row * 512;
  else {
    const float* basep = (s == 0) ? xp : (s == 1) ? sp : tp;
    int len = (s == 2) ? 77 : 300;
    in = basep + ((long)b * len + p) * 512;
  }
  int t = threadIdx.x;
  float v0 = in[t], v1 = in[t + 256];
  float s1 = v0 + v1, s2 = v0 * v0 + v1 * v1;
  #pragma unroll
  for (int d = 32; d; d >>= 1) { s1 += __shfl_xor(s1, d); s2 += __shfl_xor(s2, d); }
  __shared__ float r1[4], r2[4];
  int wid = t >> 6, lane = t & 63;
  if (lane == 0) { r1[wid] = s1; r2[wid] = s2; }
  __syncthreads();
  float S = r1[0] + r1[1] + r1[2] + r1[3];
  float Q = r2[0] + r2[1] + r2[2] + r2[3];
  float mean = S * (1.f / 512.f);
  float var = Q * (1.f / 512.f) - mean * mean;
  float rstd = rsqrtf(var + 1e-6f);
  const float* ap = ada + ((long)s * 16 + b) * 3072 + chunk * 512;
  float sh0 = ap[t], sh1 = ap[t + 256];
  float sc0 = ap[512 + t], sc1 = ap[512 + t + 256];
  long ob = (long)row * 512;
  outp[ob + t]       = f2bf((v0 - mean) * rstd * (1.f + sc0) + sh0);
  outp[ob + t + 256] = f2bf((v1 - mean) * rstd * (1.f + sc1) + sh1);
}

// ---------------- 128x128 MFMA GEMM (m97 structure) ---------------------------
template <int EPI>
__global__ __launch_bounds__(256) void k_gemm128(const unsigned short* __restrict__ A,
    const unsigned short* __restrict__ Wt, const float* __restrict__ bias,
    float* __restrict__ outF, unsigned short* __restrict__ outB,
    const float* __restrict__ hread, const float* __restrict__ ada,
    const float* __restrict__ xp, const float* __restrict__ sp, const float* __restrict__ tp,
    int K, int N) {
  int s = blockIdx.z;
  int mt = blockIdx.y;
  int Mtiles = (s == 2) ? 10 : 38;
  if (mt >= Mtiles) return;
  int Ms = (s == 2) ? 1232 : 4800;
  int rowbase = s * 4800;
  int m0 = mt * 128, n0 = blockIdx.x * 128;
  __shared__ unsigned short As[2][4096];
  __shared__ unsigned short Bs[2][4096];
  int tid = threadIdx.x;
  int w = tid >> 6, lane = tid & 63;
  int wr = w >> 1, wc = w & 1;
  int l16 = lane & 15, lg = lane >> 4;
  const unsigned short* Ag = A + (long)rowbase * K;
  const unsigned short* Bg = Wt + (long)s * N * K;
  int lrow = lane >> 2, lcol = (lane & 3) * 8;
  int ar[2], br[2];
  #pragma unroll
  for (int rnd = 0; rnd < 2; rnd++) {
    int rr = (w * 2 + rnd) * 16 + lrow;
    int a_ = m0 + rr; if (a_ >= Ms) a_ = Ms - 1;
    ar[rnd] = a_;
    br[rnd] = n0 + rr;
  }
  f32x4 acc[4][4];
  #pragma unroll
  for (int i = 0; i < 4; i++)
    #pragma unroll
    for (int j = 0; j < 4; j++) acc[i][j] = (f32x4){0.f, 0.f, 0.f, 0.f};
  #pragma unroll
  for (int rnd = 0; rnd < 2; rnd++) {
    gld16(Ag + (long)ar[rnd] * K + lcol, &As[0][(w * 2 + rnd) * 512]);
    gld16(Bg + (long)br[rnd] * K + lcol, &Bs[0][(w * 2 + rnd) * 512]);
  }
  vmdrain();
  __syncthreads();
  int buf = 0;
  for (int k0 = 0; k0 < K; k0 += 32) {
    int nx = k0 + 32;
    if (nx < K) {
      #pragma unroll
      for (int rnd = 0; rnd < 2; rnd++) {
        gld16(Ag + (long)ar[rnd] * K + nx + lcol, &As[buf ^ 1][(w * 2 + rnd) * 512]);
        gld16(Bg + (long)br[rnd] * K + nx + lcol, &Bs[buf ^ 1][(w * 2 + rnd) * 512]);
      }
    }
    bf8 af[4], bv[4];
    #pragma unroll
    for (int i = 0; i < 4; i++) {
      af[i] = *(const bf8*)&As[buf][(wr * 64 + i * 16 + l16) * 32 + lg * 8];
      bv[i] = *(const bf8*)&Bs[buf][(wc * 64 + i * 16 + l16) * 32 + lg * 8];
    }
    #pragma unroll
    for (int i = 0; i < 4; i++)
      #pragma unroll
      for (int j = 0; j < 4; j++)
        acc[i][j] = MFMA(af[i], bv[j], acc[i][j]);
    vmdrain();
    __syncthreads();
    buf ^= 1;
  }
  #pragma unroll
  for (int i = 0; i < 4; i++) {
    #pragma unroll
    for (int r = 0; r < 4; r++) {
      int rloc = m0 + wr * 64 + i * 16 + lg * 4 + r;
      if (rloc >= Ms) continue;
      int grow = rowbase + rloc;
      int b, p;
      if (s == 2) { b = rloc / 77;  p = rloc - b * 77; }
      else        { b = rloc / 300; p = rloc - b * 300; }
      #pragma unroll
      for (int j = 0; j < 4; j++) {
        int col = n0 + wc * 64 + j * 16 + l16;
        float v = acc[i][j][r] + bias[s * N + col];
        if constexpr (EPI == 0) {
          outB[(long)grow * 1536 + col] = f2bf(v);
        } else if constexpr (EPI == 1) {
          const float* basep = (s == 0) ? xp : (s == 1) ? sp : tp;
          int len = (s == 2) ? 77 : 300;
          float iv = basep[((long)b * len + p) * 512 + col];
          float ga = ada[((long)s * 16 + b) * 3072 + 1024 + col];
          outF[(long)grow * 512 + col] = iv + ga * v;
        } else {
          float hv = hread[(long)grow * 512 + col];
          float gm = ada[((long)s * 16 + b) * 3072 + 2560 + col];
          int l = ((s == 0) ? 377 : (s == 1) ? 77 : 0) + p;
          outF[((long)b * 677 + l) * 512 + col] = hv + gm * v;
        }
      }
    }
  }
}

// ---------------- FF1 GEMM (128x64 lin + 128x64 gate) + fused GEGLU -----------
__global__ __launch_bounds__(256) void k_geglu128(const unsigned short* __restrict__ A,
    const unsigned short* __restrict__ Wt, const float* __restrict__ bias,
    unsigned short* __restrict__ gout) {
  int s = blockIdx.z;
  int mt = blockIdx.y;
  int Mtiles = (s == 2) ? 10 : 38;
  if (mt >= Mtiles) return;
  int Ms = (s == 2) ? 1232 : 4800;
  int rowbase = s * 4800;
  int m0 = mt * 128, n0 = blockIdx.x * 64;
  __shared__ unsigned short As[2][4096];
  __shared__ unsigned short Bl[2][2048];
  __shared__ unsigned short Bg[2][2048];
  int tid = threadIdx.x;
  int w = tid >> 6, lane = tid & 63;
  int l16 = lane & 15, lg = lane >> 4;
  const unsigned short* Ag = A + (long)rowbase * 512;
  const unsigned short* Ws = Wt + (long)s * 4096 * 512;
  int lrow = lane >> 2, lcol = (lane & 3) * 8;
  int ar[2];
  #pragma unroll
  for (int rnd = 0; rnd < 2; rnd++) {
    int a_ = m0 + (w * 2 + rnd) * 16 + lrow; if (a_ >= Ms) a_ = Ms - 1;
    ar[rnd] = a_;
  }
  int blr = n0 + w * 16 + lrow;
  int bgr = 2048 + n0 + w * 16 + lrow;
  f32x4 accl[2][4], accg[2][4];
  #pragma unroll
  for (int i = 0; i < 2; i++)
    #pragma unroll
    for (int j = 0; j < 4; j++) {
      accl[i][j] = (f32x4){0.f, 0.f, 0.f, 0.f};
      accg[i][j] = (f32x4){0.f, 0.f, 0.f, 0.f};
    }
  #pragma unroll
  for (int rnd = 0; rnd < 2; rnd++)
    gld16(Ag + (long)ar[rnd] * 512 + lcol, &As[0][(w * 2 + rnd) * 512]);
  gld16(Ws + (long)blr * 512 + lcol, &Bl[0][w * 512]);
  gld16(Ws + (long)bgr * 512 + lcol, &Bg[0][w * 512]);
  vmdrain();
  __syncthreads();
  int buf = 0;
  for (int k0 = 0; k0 < 512; k0 += 32) {
    int nx = k0 + 32;
    if (nx < 512) {
      #pragma unroll
      for (int rnd = 0; rnd < 2; rnd++)
        gld16(Ag + (long)ar[rnd] * 512 + nx + lcol, &As[buf ^ 1][(w * 2 + rnd) * 512]);
      gld16(Ws + (long)blr * 512 + nx + lcol, &Bl[buf ^ 1][w * 512]);
      gld16(Ws + (long)bgr * 512 + nx + lcol, &Bg[buf ^ 1][w * 512]);
    }
    bf8 af[2], bl[4], bg[4];
    #pragma unroll
    for (int i = 0; i < 2; i++)
      af[i] = *(const bf8*)&As[buf][(w * 32 + i * 16 + l16) * 32 + lg * 8];
    #pragma unroll
    for (int j = 0; j < 4; j++) {
      bl[j] = *(const bf8*)&Bl[buf][(j * 16 + l16) * 32 + lg * 8];
      bg[j] = *(const bf8*)&Bg[buf][(j * 16 + l16) * 32 + lg * 8];
    }
    #pragma unroll
    for (int i = 0; i < 2; i++)
      #pragma unroll
      for (int j = 0; j < 4; j++) {
        accl[i][j] = MFMA(af[i], bl[j], accl[i][j]);
        accg[i][j] = MFMA(af[i], bg[j], accg[i][j]);
      }
    vmdrain();
    __syncthreads();
    buf ^= 1;
  }
  #pragma unroll
  for (int i = 0; i < 2; i++) {
    #pragma unroll
    for (int r = 0; r < 4; r++) {
      int rloc = m0 + w * 32 + i * 16 + lg * 4 + r;
      if (rloc >= Ms) continue;
      int grow = rowbase + rloc;
      #pragma unroll
      for (int j = 0; j < 4; j++) {
        int col = n0 + j * 16 + l16;
        float lv = accl[i][j][r] + bias[s * 4096 + col];
        float gv = accg[i][j][r] + bias[s * 4096 + 2048 + col];
        float g  = lv * 0.5f * gv * (1.f + erff(gv * 0.70710678118654752f));
        gout[(long)grow * 2048 + col] = f2bf(g);
      }
    }
  }
}

// ---------------- RMS-norm + rope/pos-embed + attention layout ----------------
__global__ __launch_bounds__(256) void k_rmsrope(const unsigned short* __restrict__ qkv,
    const float* __restrict__ gqk, const float* __restrict__ posq, const float* __restrict__ posk,
    const float* __restrict__ rcos, const float* __restrict__ rsin, const float* __restrict__ rscl,
    unsigned short* __restrict__ qb, unsigned short* __restrict__ kb,
    unsigned short* __restrict__ vtb) {
  int gw = (blockIdx.x * 256 + threadIdx.x) >> 6;
  int lane = threadIdx.x & 63;
  int token = gw >> 3, h = gw & 7;
  if (token >= TOK) return;
  int s, b, p; decode_row(token, s, b, p);
  long base = (long)token * 1536 + h * 64 + lane;
  float q = bf2f(qkv[base]);
  float k = bf2f(qkv[base + 512]);
  float v = bf2f(qkv[base + 1024]);
  float sq = q * q, sk = k * k;
  #pragma unroll
  for (int d = 32; d; d >>= 1) { sq += __shfl_xor(sq, d); sk += __shfl_xor(sk, d); }
  q *= rsqrtf(sq * (1.f / 64.f) + 1e-6f) * gqk[s * 128 + lane];
  k *= rsqrtf(sk * (1.f / 64.f) + 1e-6f) * gqk[s * 128 + 64 + lane];
  int l;
  if (s == 2) {
    l = p;
    q += posq[p * 64 + lane];
    k += posk[p * 64 + lane];
  } else {
    l = (s == 1 ? 77 : 377) + p;
    int pr = lane >> 1;
    float c = rcos[p * 32 + pr], sn = rsin[p * 32 + pr], sc = rscl[p * 32 + pr];
    float qo = __shfl_xor(q, 1), ko = __shfl_xor(k, 1);
    float sgn = (lane & 1) ? 1.f : -1.f;
    q = (q * c + sgn * qo * sn) * sc;
    k = (k * c + sgn * ko * sn) / sc;
  }
  long bh = (long)(b * 8 + h);
  long qi = (bh * 704 + l) * 64 + lane;
  qb[qi] = f2bf(q);
  kb[qi] = f2bf(k);
  vtb[(bh * 64 + lane) * 704 + l] = f2bf(v);
}

// ---------------- flash attention: LDS-staged K/V tiles, 8 waves/block --------
// Block = 128 Q rows (8 waves x 16). K/V tiles [64x64] double-buffered in LDS,
// staged via global_load_lds (T2 XOR swizzle: col ^= (row&7)<<4, pre-swizzled
// global source + swizzled LDS reads). Swapped-operand QK^T, static-max softmax.
__global__ __launch_bounds__(512, 8) void k_attn(const unsigned short* __restrict__ qb,
    const unsigned short* __restrict__ kb, const unsigned short* __restrict__ vtb,
    const int* __restrict__ valid, unsigned short* __restrict__ ob) {
  __shared__ unsigned short Kb[2][4096];   // [64 rows][64 d] swizzled (8KB)
  __shared__ unsigned short Vb[2][4096];   // [64 d][64 keys] swizzled (8KB)
  __shared__ unsigned char maskv[704];
  int f0 = blockIdx.x;
  int fp = (f0 & 7) * 96 + (f0 >> 3);      // XCD-chunked bijective swizzle (768 = 8*96)
  int bh = fp / 6, qtile = fp - bh * 6;
  int b = bh >> 3, h = bh & 7;
  int tid = threadIdx.x;
  for (int i = tid; i < 704; i += 512)
    maskv[i] = (i < 677) ? (unsigned char)(valid[b * 677 + i] != 0) : (unsigned char)0;
  int w = tid >> 6, lane = tid & 63;
  int l16 = lane & 15, lg = lane >> 4;
  int qt = qtile * 128 + w * 16;
  int qrow = qt + l16;
  int qrc = qrow > 703 ? 703 : qrow;
  const unsigned short* qbase = qb + (long)bh * 704 * 64;
  const unsigned short* kbase = kb + (long)bh * 704 * 64;
  const unsigned short* vbase = vtb + (long)bh * 64 * 704;
  bf8 qf0 = *(const bf8*)(qbase + qrc * 64 + lg * 8);
  bf8 qf1 = *(const bf8*)(qbase + qrc * 64 + 32 + lg * 8);
  // staging: wave w covers rows w*8..w*8+7; lane -> (row = w*8+lane/8, col16 = lane%8)
  // source col pre-swizzled so linear gld_lds dst yields LDS[row][c ^ ((row&7)<<4)]
  int scol = (((lane & 7) << 4) ^ ((lane >> 3) << 4)) >> 1;   // ushort units
  int srow = w * 8 + (lane >> 3);
  const unsigned short* ksrc = kbase + srow * 64 + scol;      // + kt*64 per tile
  const unsigned short* vsrc = vbase + srow * 704 + scol;     // + kt per tile
  unsigned short* kd0 = &Kb[0][w * 512];
  unsigned short* kd1 = &Kb[1][w * 512];
  unsigned short* vd0 = &Vb[0][w * 512];
  unsigned short* vd1 = &Vb[1][w * 512];
  // prologue: tile 0
  gld16(ksrc, kd0);
  gld16(vsrc, vd0);
  vmdrain();
  __syncthreads();
  int mq = maskv[qrc];
  int sw = (l16 & 7) << 4;                                    // read-side swizzle (bytes)
  float lsum = 0.f;
  f32x4 Oc[4];
  #pragma unroll
  for (int df = 0; df < 4; df++) Oc[df] = (f32x4){0.f, 0.f, 0.f, 0.f};
  union U { bf8 v; unsigned u[4]; uint2 d[2]; };
  int buf = 0;
  for (int t = 0; t < 11; t++) {
    if (t < 10) {
      int ktn = (t + 1) * 64;
      gld16(ksrc + ktn * 64, buf ? kd0 : kd1);
      gld16(vsrc + ktn, buf ? vd0 : vd1);
    }
    int kt = t * 64;
    const unsigned short* Kc = Kb[buf];
    const unsigned short* Vc = Vb[buf];
    float psum = 0.f;
    unsigned pk[4][2];
    #pragma unroll
    for (int f = 0; f < 4; f++) {
      int row = f * 16 + l16;
      f32x4 sa = (f32x4){0.f, 0.f, 0.f, 0.f};
      sa = MFMA(*(const bf8*)&Kc[(row * 128 + ((lg * 16) ^ sw)) >> 1], qf0, sa);
      sa = MFMA(*(const bf8*)&Kc[(row * 128 + ((lg * 16 + 64) ^ sw)) >> 1], qf1, sa);
      unsigned mw = *(const unsigned*)&maskv[kt + f * 16 + lg * 4];
      float pr[4];
      #pragma unroll
      for (int r = 0; r < 4; r++) {
        int key = kt + f * 16 + lg * 4 + r;
        bool ok = ((mq & (mw >> (8 * r))) & 1) || (key == qrow);
        float sv = ok ? fmaf(sa[r], 0.125f, -20.f) : -1e30f;
        float pv = __expf(sv);
        pr[r] = pv;
        psum += pv;
      }
      pk[f][0] = cvtpk(pr[0], pr[1]);
      pk[f][1] = cvtpk(pr[2], pr[3]);
    }
    psum += __shfl_xor(psum, 16);
    psum += __shfl_xor(psum, 32);
    lsum += psum;
    #pragma unroll
    for (int c = 0; c < 2; c++) {
      U pu;
      pu.u[0] = pk[2 * c][0]; pu.u[1] = pk[2 * c][1];
      pu.u[2] = pk[2 * c + 1][0]; pu.u[3] = pk[2 * c + 1][1];
      #pragma unroll
      for (int df = 0; df < 4; df++) {
        int row = df * 16 + l16;
        U vu;
        vu.d[0] = *(const uint2*)&Vc[(row * 128 + ((c * 64 + lg * 8) ^ sw)) >> 1];
        vu.d[1] = *(const uint2*)&Vc[(row * 128 + ((c * 64 + lg * 8 + 32) ^ sw)) >> 1];
        Oc[df] = MFMA(vu.v, pu.v, Oc[df]);
      }
    }
    vmdrain();
    __syncthreads();
    buf ^= 1;
  }
  if (qrow < 677) {
    float inv = 1.f / fmaxf(lsum, 1e-30f);
    int l = qrow;
    int orow = (l < 77) ? 9600 + b * 77 + l
             : (l < 377) ? 4800 + b * 300 + (l - 77)
                         : b * 300 + (l - 377);
    unsigned short* op = ob + (long)orow * 512 + h * 64;
    #pragma unroll
    for (int df = 0; df < 4; df++) {
      uint2 st;
      st.x = cvtpk(Oc[df][0] * inv, Oc[df][1] * inv);
      st.y = cvtpk(Oc[df][2] * inv, Oc[df][3] * inv);
      *(uint2*)(op + df * 16 + lg * 4) = st;
    }
  }
}

// -----------------------------------------------------------------------------
extern "C" void kernel_launch(void* const* d_in, const int* in_sizes, int n_in,
                              void* d_out, int out_size, void* d_ws, size_t ws_size,
                              hipStream_t stream) {
  const float* xp   = (const float*)d_in[0];
  const float* sp   = (const float*)d_in[1];
  const float* tp   = (const float*)d_in[2];
  const float* temb = (const float*)d_in[3];
  const float* Wqkv = (const float*)d_in[4];
  const float* bqkv = (const float*)d_in[5];
  const float* Wo   = (const float*)d_in[6];
  const float* bo   = (const float*)d_in[7];
  const float* gqk  = (const float*)d_in[8];
  const float* Wada = (const float*)d_in[9];
  const float* bada = (const float*)d_in[10];
  const float* Wff1 = (const float*)d_in[11];
  const float* bff1 = (const float*)d_in[12];
  const float* Wff2 = (const float*)d_in[13];
  const float* bff2 = (const float*)d_in[14];
  const float* posq = (const float*)d_in[15];
  const float* posk = (const float*)d_in[16];
  const int*   valid= (const int*)d_in[17];
  float* out = (float*)d_out;

  char* w = (char*)d_ws;
  size_t off = 0;
  auto take = [&](size_t bytes) -> char* {
    char* p = w + off;
    off = (off + bytes + 255) & ~(size_t)255;
    return p;
  };
  unsigned short* wqkvT = (unsigned short*)take(3UL * 1536 * 512 * 2);
  unsigned short* woT   = (unsigned short*)take(3UL * 512 * 512 * 2);
  unsigned short* wff1T = (unsigned short*)take(3UL * 4096 * 512 * 2);
  unsigned short* wff2T = (unsigned short*)take(3UL * 512 * 2048 * 2);
  float*          adab  = (float*)take(3UL * 16 * 3072 * 4);
  float*          rcosb = (float*)take(300UL * 32 * 4);
  float*          rsinb = (float*)take(300UL * 32 * 4);
  float*          rsclb = (float*)take(300UL * 32 * 4);
  unsigned short* nbuf  = (unsigned short*)take((size_t)TOK * 512 * 2);
  unsigned short* qkvb  = (unsigned short*)take((size_t)TOK * 1536 * 2);
  unsigned short* qbf   = (unsigned short*)take(16UL * 8 * 704 * 64 * 2);
  unsigned short* kbf   = (unsigned short*)take(16UL * 8 * 704 * 64 * 2);
  unsigned short* vtb   = (unsigned short*)take(16UL * 8 * 64 * 704 * 2);
  unsigned short* obuf  = (unsigned short*)take((size_t)TOK * 512 * 2);
  float*          hb    = (float*)take((size_t)TOK * 512 * 4);
  unsigned short* n2b   = (unsigned short*)take((size_t)TOK * 512 * 2);
  unsigned short* gbuf  = (unsigned short*)take((size_t)TOK * 2048 * 2);
  (void)ws_size; (void)in_sizes; (void)n_in; (void)out_size;

  k_transpose<<<dim3(16, 16, 9), dim3(32, 8), 0, stream>>>(Wqkv, wqkvT, 512, 512, 262144L, 262144L);
  k_transpose<<<dim3(16, 16, 3), dim3(32, 8), 0, stream>>>(Wo, woT, 512, 512, 262144L, 262144L);
  k_transpose<<<dim3(128, 16, 3), dim3(32, 8), 0, stream>>>(Wff1, wff1T, 512, 4096, 2097152L, 2097152L);
  k_transpose<<<dim3(16, 64, 3), dim3(32, 8), 0, stream>>>(Wff2, wff2T, 2048, 512, 1048576L, 1048576L);
  k_ada<<<dim3(12, 3), 256, 0, stream>>>(temb, Wada, bada, adab);
  k_rope_tab<<<38, 256, 0, stream>>>(rcosb, rsinb, rsclb);
  k_padzero<<<128, 256, 0, stream>>>(qbf, kbf, vtb);
  k_lnmod<<<TOK, 256, 0, stream>>>(xp, sp, tp, nullptr, adab, nbuf, 0);
  k_gemm128<0><<<dim3(12, 38, 3), 256, 0, stream>>>(nbuf, wqkvT, bqkv, nullptr, qkvb, nullptr,
                                                    adab, xp, sp, tp, 512, 1536);
  k_rmsrope<<<21664, 256, 0, stream>>>(qkvb, gqk, posq, posk, rcosb, rsinb, rsclb, qbf, kbf, vtb);
  k_attn<<<768, 512, 0, stream>>>(qbf, kbf, vtb, valid, obuf);
  k_gemm128<1><<<dim3(4, 38, 3), 256, 0, stream>>>(obuf, woT, bo, hb, nullptr, nullptr,
                                                   adab, xp, sp, tp, 512, 512);
  k_lnmod<<<TOK, 256, 0, stream>>>(xp, sp, tp, hb, adab, n2b, 3);
  k_geglu128<<<dim3(32, 38, 3), 256, 0, stream>>>(n2b, wff1T, bff1, gbuf);
  k_gemm128<2><<<dim3(4, 38, 3), 256, 0, stream>>>(gbuf, wff2T, bff2, out, nullptr, hb,
                                                   adab, xp, sp, tp, 2048, 512);
}

// Round 5
// 470.793 us; speedup vs baseline: 1.4432x; 1.1691x over previous
//
#include <hip/hip_runtime.h>
#include <math.h>

#define DEV __device__ __forceinline__

typedef short bf8 __attribute__((ext_vector_type(8)));   // 8 bf16 raw bits (4 VGPRs)
typedef float f32x4 __attribute__((ext_vector_type(4)));

#define TOK 10832

DEV unsigned short f2bf(float f) {
  union { float f; unsigned u; } x; x.f = f;
  unsigned r = x.u + 0x7fffu + ((x.u >> 16) & 1u);
  return (unsigned short)(r >> 16);
}
DEV float bf2f(unsigned short h) {
  union { unsigned u; float f; } x; x.u = ((unsigned)h) << 16; return x.f;
}
DEV unsigned cvtpk(float lo, float hi) {
  unsigned r;
  asm("v_cvt_pk_bf16_f32 %0, %1, %2" : "=v"(r) : "v"(lo), "v"(hi));
  return r;
}
DEV void decode_row(int row, int& s, int& b, int& p) {
  if (row < 4800)      { s = 0; b = row / 300; p = row - b * 300; }
  else if (row < 9600) { s = 1; int r = row - 4800; b = r / 300; p = r - b * 300; }
  else                 { s = 2; int r = row - 9600; b = r / 77;  p = r - b * 77; }
}
DEV f32x4 MFMA(bf8 a, bf8 b, f32x4 c) {
  return __builtin_amdgcn_mfma_f32_16x16x32_bf16(a, b, c, 0, 0, 0);
}
DEV void gld16(const unsigned short* g, unsigned short* l) {
  __builtin_amdgcn_global_load_lds((const __attribute__((address_space(1))) unsigned int*)g,
                                   (__attribute__((address_space(3))) unsigned int*)l,
                                   16, 0, 0);
}
DEV void vmdrain() { asm volatile("s_waitcnt vmcnt(0)" ::: "memory"); }

// ---------------- weight transpose + fp32->bf16: dst[c][r] = src[r][c] --------
__global__ __launch_bounds__(256) void k_transpose(const float* __restrict__ src,
                                                   unsigned short* __restrict__ dst,
                                                   int R, int C, long sstride, long dstride) {
  __shared__ float t[32][33];
  const float* s = src + (long)blockIdx.z * sstride;
  unsigned short* d = dst + (long)blockIdx.z * dstride;
  int c0 = blockIdx.x * 32, r0 = blockIdx.y * 32;
  int tx = threadIdx.x, ty = threadIdx.y;
  #pragma unroll
  for (int i = ty; i < 32; i += 8) t[i][tx] = s[(long)(r0 + i) * C + c0 + tx];
  __syncthreads();
  #pragma unroll
  for (int i = ty; i < 32; i += 8) d[(long)(c0 + i) * R + r0 + tx] = f2bf(t[tx][i]);
}

// ---------------- ada stage 1: split-K partial sums ---------------------------
// part[kc][s][b][e] = sum_{d in kc-slice} silu(temb[b][d]) * Wada[s][d][e]
__global__ __launch_bounds__(256) void k_ada1(const float* __restrict__ temb,
    const float* __restrict__ Wada, float* __restrict__ part) {
  __shared__ float st[16][64];
  int s = blockIdx.y, kc = blockIdx.z;
  int e = blockIdx.x * 256 + threadIdx.x;
  int d0 = kc * 64;
  for (int i = threadIdx.x; i < 16 * 64; i += 256) {
    int b = i >> 6, d = i & 63;
    float v = temb[b * 512 + d0 + d];
    st[b][d] = v / (1.f + __expf(-v));
  }
  __syncthreads();
  float acc[16];
  #pragma unroll
  for (int b = 0; b < 16; b++) acc[b] = 0.f;
  const float* wp = Wada + (long)s * 512 * 3072 + (long)d0 * 3072 + e;
  for (int d = 0; d < 64; d++) {
    float wv = wp[(long)d * 3072];
    #pragma unroll
    for (int b = 0; b < 16; b++) acc[b] += st[b][d] * wv;
  }
  float* pp = part + (((long)kc * 3 + s) * 16) * 3072 + e;
  #pragma unroll
  for (int b = 0; b < 16; b++) pp[(long)b * 3072] = acc[b];
}

// ---------------- ada stage 2: reduce 8 partials + bias -----------------------
__global__ __launch_bounds__(256) void k_ada2(const float* __restrict__ part,
    const float* __restrict__ bada, float* __restrict__ ada) {
  int idx = blockIdx.x * 256 + threadIdx.x;      // over 3*16*3072
  int e = idx % 3072, sb = idx / 3072, s = sb >> 4;
  float a = bada[s * 3072 + e];
  #pragma unroll
  for (int kc = 0; kc < 8; kc++) a += part[((long)kc * 48 + sb) * 3072 + e];
  ada[idx] = a;
}

// ---------------- rope tables (xpos) ------------------------------------------
__global__ __launch_bounds__(256) void k_rope_tab(float* __restrict__ rc,
    float* __restrict__ rs, float* __restrict__ rsc) {
  int i = blockIdx.x * 256 + threadIdx.x;
  if (i >= 300 * 32) return;
  int p = i >> 5, f = i & 31;
  float inv = powf(10000.f, -(2.f * f) / 64.f);
  float ang = (float)p * inv;
  float base = (2.f * f + 25.6f) / 89.6f;
  float pw = (float)(p - 150) * (1.f / 512.f);
  rc[i] = cosf(ang);
  rs[i] = sinf(ang);
  rsc[i] = powf(base, pw);
}

// ---------------- zero attention padding (rows/cols 677..703) -----------------
__global__ __launch_bounds__(256) void k_padzero(unsigned short* __restrict__ qb,
    unsigned short* __restrict__ kb, unsigned short* __restrict__ vtb) {
  int bh = blockIdx.x, t = threadIdx.x;
  for (int i = t; i < 27 * 64; i += 256) {
    int r = 677 + (i >> 6), c = i & 63;
    long idx = ((long)bh * 704 + r) * 64 + c;
    qb[idx] = 0; kb[idx] = 0;
  }
  for (int i = t; i < 64 * 27; i += 256) {
    int r = i / 27, c = 677 + (i - r * 27);
    vtb[((long)bh * 64 + r) * 704 + c] = 0;
  }
}

// ---------------- LayerNorm + AdaLN modulate -> bf16 rows ---------------------
__global__ __launch_bounds__(256) void k_lnmod(const float* __restrict__ xp,
    const float* __restrict__ sp, const float* __restrict__ tp,
    const float* __restrict__ hbuf, const float* __restrict__ ada,
    unsigned short* __restrict__ outp, int chunk) {
  int row = blockIdx.x;
  int s, b, p; decode_row(row, s, b, p);
  const float* in;
  if (hbuf) in = hbuf + (long)row * 512;
  else {
    const float* basep = (s == 0) ? xp : (s == 1) ? sp : tp;
    int len = (s == 2) ? 77 : 300;
    in = basep + ((long)b * len + p) * 512;
  }
  int t = threadIdx.x;
  float v0 = in[t], v1 = in[t + 256];
  float s1 = v0 + v1, s2 = v0 * v0 + v1 * v1;
  #pragma unroll
  for (int d = 32; d; d >>= 1) { s1 += __shfl_xor(s1, d); s2 += __shfl_xor(s2, d); }
  __shared__ float r1[4], r2[4];
  int wid = t >> 6, lane = t & 63;
  if (lane == 0) { r1[wid] = s1; r2[wid] = s2; }
  __syncthreads();
  float S = r1[0] + r1[1] + r1[2] + r1[3];
  float Q = r2[0] + r2[1] + r2[2] + r2[3];
  float mean = S * (1.f / 512.f);
  float var = Q * (1.f / 512.f) - mean * mean;
  float rstd = rsqrtf(var + 1e-6f);
  const float* ap = ada + ((long)s * 16 + b) * 3072 + chunk * 512;
  float sh0 = ap[t], sh1 = ap[t + 256];
  float sc0 = ap[512 + t], sc1 = ap[512 + t + 256];
  long ob = (long)row * 512;
  outp[ob + t]       = f2bf((v0 - mean) * rstd * (1.f + sc0) + sh0);
  outp[ob + t + 256] = f2bf((v1 - mean) * rstd * (1.f + sc1) + sh1);
}

// ---------------- 128x128 MFMA GEMM (m97 structure) ---------------------------
template <int EPI>
__global__ __launch_bounds__(256) void k_gemm128(const unsigned short* __restrict__ A,
    const unsigned short* __restrict__ Wt, const float* __restrict__ bias,
    float* __restrict__ outF, unsigned short* __restrict__ outB,
    const float* __restrict__ hread, const float* __restrict__ ada,
    const float* __restrict__ xp, const float* __restrict__ sp, const float* __restrict__ tp,
    int K, int N) {
  int s = blockIdx.z;
  int mt = blockIdx.y;
  int Mtiles = (s == 2) ? 10 : 38;
  if (mt >= Mtiles) return;
  int Ms = (s == 2) ? 1232 : 4800;
  int rowbase = s * 4800;
  int m0 = mt * 128, n0 = blockIdx.x * 128;
  __shared__ unsigned short As[2][4096];
  __shared__ unsigned short Bs[2][4096];
  int tid = threadIdx.x;
  int w = tid >> 6, lane = tid & 63;
  int wr = w >> 1, wc = w & 1;
  int l16 = lane & 15, lg = lane >> 4;
  const unsigned short* Ag = A + (long)rowbase * K;
  const unsigned short* Bg = Wt + (long)s * N * K;
  int lrow = lane >> 2, lcol = (lane & 3) * 8;
  int ar[2], br[2];
  #pragma unroll
  for (int rnd = 0; rnd < 2; rnd++) {
    int rr = (w * 2 + rnd) * 16 + lrow;
    int a_ = m0 + rr; if (a_ >= Ms) a_ = Ms - 1;
    ar[rnd] = a_;
    br[rnd] = n0 + rr;
  }
  f32x4 acc[4][4];
  #pragma unroll
  for (int i = 0; i < 4; i++)
    #pragma unroll
    for (int j = 0; j < 4; j++) acc[i][j] = (f32x4){0.f, 0.f, 0.f, 0.f};
  #pragma unroll
  for (int rnd = 0; rnd < 2; rnd++) {
    gld16(Ag + (long)ar[rnd] * K + lcol, &As[0][(w * 2 + rnd) * 512]);
    gld16(Bg + (long)br[rnd] * K + lcol, &Bs[0][(w * 2 + rnd) * 512]);
  }
  vmdrain();
  __syncthreads();
  int buf = 0;
  for (int k0 = 0; k0 < K; k0 += 32) {
    int nx = k0 + 32;
    if (nx < K) {
      #pragma unroll
      for (int rnd = 0; rnd < 2; rnd++) {
        gld16(Ag + (long)ar[rnd] * K + nx + lcol, &As[buf ^ 1][(w * 2 + rnd) * 512]);
        gld16(Bg + (long)br[rnd] * K + nx + lcol, &Bs[buf ^ 1][(w * 2 + rnd) * 512]);
      }
    }
    bf8 af[4], bv[4];
    #pragma unroll
    for (int i = 0; i < 4; i++) {
      af[i] = *(const bf8*)&As[buf][(wr * 64 + i * 16 + l16) * 32 + lg * 8];
      bv[i] = *(const bf8*)&Bs[buf][(wc * 64 + i * 16 + l16) * 32 + lg * 8];
    }
    #pragma unroll
    for (int i = 0; i < 4; i++)
      #pragma unroll
      for (int j = 0; j < 4; j++)
        acc[i][j] = MFMA(af[i], bv[j], acc[i][j]);
    vmdrain();
    __syncthreads();
    buf ^= 1;
  }
  #pragma unroll
  for (int i = 0; i < 4; i++) {
    #pragma unroll
    for (int r = 0; r < 4; r++) {
      int rloc = m0 + wr * 64 + i * 16 + lg * 4 + r;
      if (rloc >= Ms) continue;
      int grow = rowbase + rloc;
      int b, p;
      if (s == 2) { b = rloc / 77;  p = rloc - b * 77; }
      else        { b = rloc / 300; p = rloc - b * 300; }
      #pragma unroll
      for (int j = 0; j < 4; j++) {
        int col = n0 + wc * 64 + j * 16 + l16;
        float v = acc[i][j][r] + bias[s * N + col];
        if constexpr (EPI == 0) {
          outB[(long)grow * 1536 + col] = f2bf(v);
        } else if constexpr (EPI == 1) {
          const float* basep = (s == 0) ? xp : (s == 1) ? sp : tp;
          int len = (s == 2) ? 77 : 300;
          float iv = basep[((long)b * len + p) * 512 + col];
          float ga = ada[((long)s * 16 + b) * 3072 + 1024 + col];
          outF[(long)grow * 512 + col] = iv + ga * v;
        } else {
          float hv = hread[(long)grow * 512 + col];
          float gm = ada[((long)s * 16 + b) * 3072 + 2560 + col];
          int l = ((s == 0) ? 377 : (s == 1) ? 77 : 0) + p;
          outF[((long)b * 677 + l) * 512 + col] = hv + gm * v;
        }
      }
    }
  }
}

// ---------------- FF1 GEMM (128x64 lin + 128x64 gate) + fused GEGLU -----------
__global__ __launch_bounds__(256) void k_geglu128(const unsigned short* __restrict__ A,
    const unsigned short* __restrict__ Wt, const float* __restrict__ bias,
    unsigned short* __restrict__ gout) {
  int s = blockIdx.z;
  int mt = blockIdx.y;
  int Mtiles = (s == 2) ? 10 : 38;
  if (mt >= Mtiles) return;
  int Ms = (s == 2) ? 1232 : 4800;
  int rowbase = s * 4800;
  int m0 = mt * 128, n0 = blockIdx.x * 64;
  __shared__ unsigned short As[2][4096];
  __shared__ unsigned short Bl[2][2048];
  __shared__ unsigned short Bg[2][2048];
  int tid = threadIdx.x;
  int w = tid >> 6, lane = tid & 63;
  int l16 = lane & 15, lg = lane >> 4;
  const unsigned short* Ag = A + (long)rowbase * 512;
  const unsigned short* Ws = Wt + (long)s * 4096 * 512;
  int lrow = lane >> 2, lcol = (lane & 3) * 8;
  int ar[2];
  #pragma unroll
  for (int rnd = 0; rnd < 2; rnd++) {
    int a_ = m0 + (w * 2 + rnd) * 16 + lrow; if (a_ >= Ms) a_ = Ms - 1;
    ar[rnd] = a_;
  }
  int blr = n0 + w * 16 + lrow;
  int bgr = 2048 + n0 + w * 16 + lrow;
  f32x4 accl[2][4], accg[2][4];
  #pragma unroll
  for (int i = 0; i < 2; i++)
    #pragma unroll
    for (int j = 0; j < 4; j++) {
      accl[i][j] = (f32x4){0.f, 0.f, 0.f, 0.f};
      accg[i][j] = (f32x4){0.f, 0.f, 0.f, 0.f};
    }
  #pragma unroll
  for (int rnd = 0; rnd < 2; rnd++)
    gld16(Ag + (long)ar[rnd] * 512 + lcol, &As[0][(w * 2 + rnd) * 512]);
  gld16(Ws + (long)blr * 512 + lcol, &Bl[0][w * 512]);
  gld16(Ws + (long)bgr * 512 + lcol, &Bg[0][w * 512]);
  vmdrain();
  __syncthreads();
  int buf = 0;
  for (int k0 = 0; k0 < 512; k0 += 32) {
    int nx = k0 + 32;
    if (nx < 512) {
      #pragma unroll
      for (int rnd = 0; rnd < 2; rnd++)
        gld16(Ag + (long)ar[rnd] * 512 + nx + lcol, &As[buf ^ 1][(w * 2 + rnd) * 512]);
      gld16(Ws + (long)blr * 512 + nx + lcol, &Bl[buf ^ 1][w * 512]);
      gld16(Ws + (long)bgr * 512 + nx + lcol, &Bg[buf ^ 1][w * 512]);
    }
    bf8 af[2], bl[4], bg[4];
    #pragma unroll
    for (int i = 0; i < 2; i++)
      af[i] = *(const bf8*)&As[buf][(w * 32 + i * 16 + l16) * 32 + lg * 8];
    #pragma unroll
    for (int j = 0; j < 4; j++) {
      bl[j] = *(const bf8*)&Bl[buf][(j * 16 + l16) * 32 + lg * 8];
      bg[j] = *(const bf8*)&Bg[buf][(j * 16 + l16) * 32 + lg * 8];
    }
    #pragma unroll
    for (int i = 0; i < 2; i++)
      #pragma unroll
      for (int j = 0; j < 4; j++) {
        accl[i][j] = MFMA(af[i], bl[j], accl[i][j]);
        accg[i][j] = MFMA(af[i], bg[j], accg[i][j]);
      }
    vmdrain();
    __syncthreads();
    buf ^= 1;
  }
  #pragma unroll
  for (int i = 0; i < 2; i++) {
    #pragma unroll
    for (int r = 0; r < 4; r++) {
      int rloc = m0 + w * 32 + i * 16 + lg * 4 + r;
      if (rloc >= Ms) continue;
      int grow = rowbase + rloc;
      #pragma unroll
      for (int j = 0; j < 4; j++) {
        int col = n0 + j * 16 + l16;
        float lv = accl[i][j][r] + bias[s * 4096 + col];
        float gv = accg[i][j][r] + bias[s * 4096 + 2048 + col];
        float g  = lv * 0.5f * gv * (1.f + erff(gv * 0.70710678118654752f));
        gout[(long)grow * 2048 + col] = f2bf(g);
      }
    }
  }
}

// ---------------- RMS-norm + rope/pos-embed + attention layout ----------------
__global__ __launch_bounds__(256) void k_rmsrope(const unsigned short* __restrict__ qkv,
    const float* __restrict__ gqk, const float* __restrict__ posq, const float* __restrict__ posk,
    const float* __restrict__ rcos, const float* __restrict__ rsin, const float* __restrict__ rscl,
    unsigned short* __restrict__ qb, unsigned short* __restrict__ kb,
    unsigned short* __restrict__ vtb) {
  int gw = (blockIdx.x * 256 + threadIdx.x) >> 6;
  int lane = threadIdx.x & 63;
  int token = gw >> 3, h = gw & 7;
  if (token >= TOK) return;
  int s, b, p; decode_row(token, s, b, p);
  long base = (long)token * 1536 + h * 64 + lane;
  float q = bf2f(qkv[base]);
  float k = bf2f(qkv[base + 512]);
  float v = bf2f(qkv[base + 1024]);
  float sq = q * q, sk = k * k;
  #pragma unroll
  for (int d = 32; d; d >>= 1) { sq += __shfl_xor(sq, d); sk += __shfl_xor(sk, d); }
  q *= rsqrtf(sq * (1.f / 64.f) + 1e-6f) * gqk[s * 128 + lane];
  k *= rsqrtf(sk * (1.f / 64.f) + 1e-6f) * gqk[s * 128 + 64 + lane];
  int l;
  if (s == 2) {
    l = p;
    q += posq[p * 64 + lane];
    k += posk[p * 64 + lane];
  } else {
    l = (s == 1 ? 77 : 377) + p;
    int pr = lane >> 1;
    float c = rcos[p * 32 + pr], sn = rsin[p * 32 + pr], sc = rscl[p * 32 + pr];
    float qo = __shfl_xor(q, 1), ko = __shfl_xor(k, 1);
    float sgn = (lane & 1) ? 1.f : -1.f;
    q = (q * c + sgn * qo * sn) * sc;
    k = (k * c + sgn * ko * sn) / sc;
  }
  long bh = (long)(b * 8 + h);
  long qi = (bh * 704 + l) * 64 + lane;
  qb[qi] = f2bf(q);
  kb[qi] = f2bf(k);
  vtb[(bh * 64 + lane) * 704 + l] = f2bf(v);
}

// ---------------- flash attention: LDS-staged K/V tiles, 8 waves/block --------
__global__ __launch_bounds__(512, 8) void k_attn(const unsigned short* __restrict__ qb,
    const unsigned short* __restrict__ kb, const unsigned short* __restrict__ vtb,
    const int* __restrict__ valid, unsigned short* __restrict__ ob) {
  __shared__ unsigned short Kb[2][4096];   // [64 rows][64 d] swizzled (8KB)
  __shared__ unsigned short Vb[2][4096];   // [64 d][64 keys] swizzled (8KB)
  __shared__ unsigned char maskv[704];
  int f0 = blockIdx.x;
  int fp = (f0 & 7) * 96 + (f0 >> 3);      // XCD-chunked bijective swizzle (768 = 8*96)
  int bh = fp / 6, qtile = fp - bh * 6;
  int b = bh >> 3, h = bh & 7;
  int tid = threadIdx.x;
  for (int i = tid; i < 704; i += 512)
    maskv[i] = (i < 677) ? (unsigned char)(valid[b * 677 + i] != 0) : (unsigned char)0;
  int w = tid >> 6, lane = tid & 63;
  int l16 = lane & 15, lg = lane >> 4;
  int qt = qtile * 128 + w * 16;
  int qrow = qt + l16;
  int qrc = qrow > 703 ? 703 : qrow;
  const unsigned short* qbase = qb + (long)bh * 704 * 64;
  const unsigned short* kbase = kb + (long)bh * 704 * 64;
  const unsigned short* vbase = vtb + (long)bh * 64 * 704;
  bf8 qf0 = *(const bf8*)(qbase + qrc * 64 + lg * 8);
  bf8 qf1 = *(const bf8*)(qbase + qrc * 64 + 32 + lg * 8);
  int scol = (((lane & 7) << 4) ^ ((lane >> 3) << 4)) >> 1;   // ushort units
  int srow = w * 8 + (lane >> 3);
  const unsigned short* ksrc = kbase + srow * 64 + scol;
  const unsigned short* vsrc = vbase + srow * 704 + scol;
  unsigned short* kd0 = &Kb[0][w * 512];
  unsigned short* kd1 = &Kb[1][w * 512];
  unsigned short* vd0 = &Vb[0][w * 512];
  unsigned short* vd1 = &Vb[1][w * 512];
  gld16(ksrc, kd0);
  gld16(vsrc, vd0);
  vmdrain();
  __syncthreads();
  int mq = maskv[qrc];
  int sw = (l16 & 7) << 4;
  float lsum = 0.f;
  f32x4 Oc[4];
  #pragma unroll
  for (int df = 0; df < 4; df++) Oc[df] = (f32x4){0.f, 0.f, 0.f, 0.f};
  union U { bf8 v; unsigned u[4]; uint2 d[2]; };
  int buf = 0;
  for (int t = 0; t < 11; t++) {
    if (t < 10) {
      int ktn = (t + 1) * 64;
      gld16(ksrc + ktn * 64, buf ? kd0 : kd1);
      gld16(vsrc + ktn, buf ? vd0 : vd1);
    }
    int kt = t * 64;
    const unsigned short* Kc = Kb[buf];
    const unsigned short* Vc = Vb[buf];
    float psum = 0.f;
    unsigned pk[4][2];
    #pragma unroll
    for (int f = 0; f < 4; f++) {
      int row = f * 16 + l16;
      f32x4 sa = (f32x4){0.f, 0.f, 0.f, 0.f};
      sa = MFMA(*(const bf8*)&Kc[(row * 128 + ((lg * 16) ^ sw)) >> 1], qf0, sa);
      sa = MFMA(*(const bf8*)&Kc[(row * 128 + ((lg * 16 + 64) ^ sw)) >> 1], qf1, sa);
      unsigned mw = *(const unsigned*)&maskv[kt + f * 16 + lg * 4];
      float pr[4];
      #pragma unroll
      for (int r = 0; r < 4; r++) {
        int key = kt + f * 16 + lg * 4 + r;
        bool ok = ((mq & (mw >> (8 * r))) & 1) || (key == qrow);
        float sv = ok ? fmaf(sa[r], 0.125f, -20.f) : -1e30f;
        float pv = __expf(sv);
        pr[r] = pv;
        psum += pv;
      }
      pk[f][0] = cvtpk(pr[0], pr[1]);
      pk[f][1] = cvtpk(pr[2], pr[3]);
    }
    psum += __shfl_xor(psum, 16);
    psum += __shfl_xor(psum, 32);
    lsum += psum;
    #pragma unroll
    for (int c = 0; c < 2; c++) {
      U pu;
      pu.u[0] = pk[2 * c][0]; pu.u[1] = pk[2 * c][1];
      pu.u[2] = pk[2 * c + 1][0]; pu.u[3] = pk[2 * c + 1][1];
      #pragma unroll
      for (int df = 0; df < 4; df++) {
        int row = df * 16 + l16;
        U vu;
        vu.d[0] = *(const uint2*)&Vc[(row * 128 + ((c * 64 + lg * 8) ^ sw)) >> 1];
        vu.d[1] = *(const uint2*)&Vc[(row * 128 + ((c * 64 + lg * 8 + 32) ^ sw)) >> 1];
        Oc[df] = MFMA(vu.v, pu.v, Oc[df]);
      }
    }
    vmdrain();
    __syncthreads();
    buf ^= 1;
  }
  if (qrow < 677) {
    float inv = 1.f / fmaxf(lsum, 1e-30f);
    int l = qrow;
    int orow = (l < 77) ? 9600 + b * 77 + l
             : (l < 377) ? 4800 + b * 300 + (l - 77)
                         : b * 300 + (l - 377);
    unsigned short* op = ob + (long)orow * 512 + h * 64;
    #pragma unroll
    for (int df = 0; df < 4; df++) {
      uint2 st;
      st.x = cvtpk(Oc[df][0] * inv, Oc[df][1] * inv);
      st.y = cvtpk(Oc[df][2] * inv, Oc[df][3] * inv);
      *(uint2*)(op + df * 16 + lg * 4) = st;
    }
  }
}

// -----------------------------------------------------------------------------
extern "C" void kernel_launch(void* const* d_in, const int* in_sizes, int n_in,
                              void* d_out, int out_size, void* d_ws, size_t ws_size,
                              hipStream_t stream) {
  const float* xp   = (const float*)d_in[0];
  const float* sp   = (const float*)d_in[1];
  const float* tp   = (const float*)d_in[2];
  const float* temb = (const float*)d_in[3];
  const float* Wqkv = (const float*)d_in[4];
  const float* bqkv = (const float*)d_in[5];
  const float* Wo   = (const float*)d_in[6];
  const float* bo   = (const float*)d_in[7];
  const float* gqk  = (const float*)d_in[8];
  const float* Wada = (const float*)d_in[9];
  const float* bada = (const float*)d_in[10];
  const float* Wff1 = (const float*)d_in[11];
  const float* bff1 = (const float*)d_in[12];
  const float* Wff2 = (const float*)d_in[13];
  const float* bff2 = (const float*)d_in[14];
  const float* posq = (const float*)d_in[15];
  const float* posk = (const float*)d_in[16];
  const int*   valid= (const int*)d_in[17];
  float* out = (float*)d_out;

  char* w = (char*)d_ws;
  size_t off = 0;
  auto take = [&](size_t bytes) -> char* {
    char* p = w + off;
    off = (off + bytes + 255) & ~(size_t)255;
    return p;
  };
  unsigned short* wqkvT = (unsigned short*)take(3UL * 1536 * 512 * 2);
  unsigned short* woT   = (unsigned short*)take(3UL * 512 * 512 * 2);
  unsigned short* wff1T = (unsigned short*)take(3UL * 4096 * 512 * 2);
  unsigned short* wff2T = (unsigned short*)take(3UL * 512 * 2048 * 2);
  float*          adab  = (float*)take(3UL * 16 * 3072 * 4);
  float*          adap  = (float*)take(8UL * 3 * 16 * 3072 * 4);
  float*          rcosb = (float*)take(300UL * 32 * 4);
  float*          rsinb = (float*)take(300UL * 32 * 4);
  float*          rsclb = (float*)take(300UL * 32 * 4);
  unsigned short* nbuf  = (unsigned short*)take((size_t)TOK * 512 * 2);
  unsigned short* qkvb  = (unsigned short*)take((size_t)TOK * 1536 * 2);
  unsigned short* qbf   = (unsigned short*)take(16UL * 8 * 704 * 64 * 2);
  unsigned short* kbf   = (unsigned short*)take(16UL * 8 * 704 * 64 * 2);
  unsigned short* vtb   = (unsigned short*)take(16UL * 8 * 64 * 704 * 2);
  unsigned short* obuf  = (unsigned short*)take((size_t)TOK * 512 * 2);
  float*          hb    = (float*)take((size_t)TOK * 512 * 4);
  unsigned short* n2b   = (unsigned short*)take((size_t)TOK * 512 * 2);
  unsigned short* gbuf  = (unsigned short*)take((size_t)TOK * 2048 * 2);
  (void)ws_size; (void)in_sizes; (void)n_in; (void)out_size;

  k_transpose<<<dim3(16, 16, 9), dim3(32, 8), 0, stream>>>(Wqkv, wqkvT, 512, 512, 262144L, 262144L);
  k_transpose<<<dim3(16, 16, 3), dim3(32, 8), 0, stream>>>(Wo, woT, 512, 512, 262144L, 262144L);
  k_transpose<<<dim3(128, 16, 3), dim3(32, 8), 0, stream>>>(Wff1, wff1T, 512, 4096, 2097152L, 2097152L);
  k_transpose<<<dim3(16, 64, 3), dim3(32, 8), 0, stream>>>(Wff2, wff2T, 2048, 512, 1048576L, 1048576L);
  k_ada1<<<dim3(12, 3, 8), 256, 0, stream>>>(temb, Wada, adap);
  k_ada2<<<576, 256, 0, stream>>>(adap, bada, adab);
  k_rope_tab<<<38, 256, 0, stream>>>(rcosb, rsinb, rsclb);
  k_padzero<<<128, 256, 0, stream>>>(qbf, kbf, vtb);
  k_lnmod<<<TOK, 256, 0, stream>>>(xp, sp, tp, nullptr, adab, nbuf, 0);
  k_gemm128<0><<<dim3(12, 38, 3), 256, 0, stream>>>(nbuf, wqkvT, bqkv, nullptr, qkvb, nullptr,
                                                    adab, xp, sp, tp, 512, 1536);
  k_rmsrope<<<21664, 256, 0, stream>>>(qkvb, gqk, posq, posk, rcosb, rsinb, rsclb, qbf, kbf, vtb);
  k_attn<<<768, 512, 0, stream>>>(qbf, kbf, vtb, valid, obuf);
  k_gemm128<1><<<dim3(4, 38, 3), 256, 0, stream>>>(obuf, woT, bo, hb, nullptr, nullptr,
                                                   adab, xp, sp, tp, 512, 512);
  k_lnmod<<<TOK, 256, 0, stream>>>(xp, sp, tp, hb, adab, n2b, 3);
  k_geglu128<<<dim3(32, 38, 3), 256, 0, stream>>>(n2b, wff1T, bff1, gbuf);
  k_gemm128<2><<<dim3(4, 38, 3), 256, 0, stream>>>(gbuf, wff2T, bff2, out, nullptr, hb,
                                                   adab, xp, sp, tp, 2048, 512);
}